// Round 1
// baseline (6416.579 us; speedup 1.0000x reference)
//
#include <hip/hip_runtime.h>

#define D 256
#define N_NODES 100000
#define N_HE 25000
#define N_CONN 400000

constexpr float MEAN_EPS = 1e-8f;
constexpr float LN_EPS   = 1e-5f;
constexpr float SLOPE    = 0.2f;

// ---------------------------------------------------------------------------
// Count degrees (same for both layers; indices are constant inputs)
// ---------------------------------------------------------------------------
__global__ __launch_bounds__(256) void count_kernel(
    const int* __restrict__ node_idx, const int* __restrict__ he_idx,
    float* __restrict__ he_cnt, float* __restrict__ n_cnt) {
  int c = blockIdx.x * 256 + threadIdx.x;
  if (c < N_CONN) {
    atomicAdd(&he_cnt[he_idx[c]], 1.0f);
    atomicAdd(&n_cnt[node_idx[c]], 1.0f);
  }
}

// ---------------------------------------------------------------------------
// Node GEMM: out[r][c] = sum_k A[r][k] * W[k][c] + bias[c]
// 32 rows per block, 256 threads (1 col/thread), A tile staged in LDS.
// ---------------------------------------------------------------------------
__global__ __launch_bounds__(256) void gemm_node(
    const float* __restrict__ A, const float* __restrict__ W,
    const float* __restrict__ bias, float* __restrict__ out, int M) {
  __shared__ float As[32][D];
  const int t = threadIdx.x;
  const int row0 = blockIdx.x * 32;

  #pragma unroll 8
  for (int j = 0; j < 32; ++j) {
    int r = row0 + j;
    As[j][t] = (r < M) ? A[(size_t)r * D + t] : 0.f;
  }
  __syncthreads();

  float acc[32];
  #pragma unroll
  for (int r = 0; r < 32; ++r) acc[r] = 0.f;

  for (int k = 0; k < D; k += 4) {
    float w0 = W[(k + 0) * D + t];
    float w1 = W[(k + 1) * D + t];
    float w2 = W[(k + 2) * D + t];
    float w3 = W[(k + 3) * D + t];
    #pragma unroll
    for (int r = 0; r < 32; ++r) {
      float4 a = *(const float4*)&As[r][k];
      acc[r] = fmaf(a.x, w0, acc[r]);
      acc[r] = fmaf(a.y, w1, acc[r]);
      acc[r] = fmaf(a.z, w2, acc[r]);
      acc[r] = fmaf(a.w, w3, acc[r]);
    }
  }

  float b = bias[t];
  #pragma unroll 8
  for (int r = 0; r < 32; ++r) {
    int rr = row0 + r;
    if (rr < M) out[(size_t)rr * D + t] = acc[r] + b;
  }
}

// ---------------------------------------------------------------------------
// Hyperedge GEMM (in-place): in = he_sum; feat = in/(cnt+eps);
// out[r][c] = (sum_k feat[r][k]*W[k][c] + be[c]) * w[r]
// Block reads its whole 32-row tile into LDS before writing -> in-place safe.
// ---------------------------------------------------------------------------
__global__ __launch_bounds__(256) void gemm_he(
    const float* __restrict__ A, const float* __restrict__ W,
    const float* __restrict__ bias, const float* __restrict__ hw,
    const float* __restrict__ cnt, float* __restrict__ out, int M) {
  __shared__ float As[32][D];
  const int t = threadIdx.x;
  const int row0 = blockIdx.x * 32;

  #pragma unroll 8
  for (int j = 0; j < 32; ++j) {
    int r = row0 + j;
    if (r < M) {
      float inv = 1.0f / (cnt[r] + MEAN_EPS);
      As[j][t] = A[(size_t)r * D + t] * inv;
    } else {
      As[j][t] = 0.f;
    }
  }
  __syncthreads();

  float acc[32];
  #pragma unroll
  for (int r = 0; r < 32; ++r) acc[r] = 0.f;

  for (int k = 0; k < D; k += 4) {
    float w0 = W[(k + 0) * D + t];
    float w1 = W[(k + 1) * D + t];
    float w2 = W[(k + 2) * D + t];
    float w3 = W[(k + 3) * D + t];
    #pragma unroll
    for (int r = 0; r < 32; ++r) {
      float4 a = *(const float4*)&As[r][k];
      acc[r] = fmaf(a.x, w0, acc[r]);
      acc[r] = fmaf(a.y, w1, acc[r]);
      acc[r] = fmaf(a.z, w2, acc[r]);
      acc[r] = fmaf(a.w, w3, acc[r]);
    }
  }

  float b = bias[t];
  #pragma unroll 8
  for (int r = 0; r < 32; ++r) {
    int rr = row0 + r;
    if (rr < M) out[(size_t)rr * D + t] = (acc[r] + b) * hw[rr];
  }
}

// ---------------------------------------------------------------------------
// Scatter-add: dst[dst_idx[c]] += src[src_idx[c]], one wave per connection,
// 4 floats per lane. 4 waves (4 connections) per block.
// ---------------------------------------------------------------------------
__global__ __launch_bounds__(256) void scatter_kernel(
    const float* __restrict__ src, const int* __restrict__ src_idx,
    const int* __restrict__ dst_idx, float* __restrict__ dst) {
  int c = blockIdx.x * 4 + (threadIdx.x >> 6);
  int lane = threadIdx.x & 63;
  int s = src_idx[c];
  int d = dst_idx[c];
  float4 v = ((const float4*)(src + (size_t)s * D))[lane];
  float* p = dst + (size_t)d * D + lane * 4;
  atomicAdd(p + 0, v.x);
  atomicAdd(p + 1, v.y);
  atomicAdd(p + 2, v.z);
  atomicAdd(p + 3, v.w);
}

// ---------------------------------------------------------------------------
// Finalize: agg = cnt>0 ? n_sum/max(cnt,1) : 0; h = agg + xt;
// h = LN(h)*g + b; h = leaky_relu(h); if(add_res) h += res. One wave per row.
// ---------------------------------------------------------------------------
__global__ __launch_bounds__(256) void finalize_kernel(
    const float* __restrict__ n_sum, const float* __restrict__ n_cnt,
    const float* __restrict__ xt, const float* __restrict__ g,
    const float* __restrict__ b, const float* __restrict__ res,
    float* __restrict__ out, int add_res) {
  int node = blockIdx.x * 4 + (threadIdx.x >> 6);
  int lane = threadIdx.x & 63;

  float cnt = n_cnt[node];
  float inv = cnt > 0.f ? 1.0f / fmaxf(cnt, 1.0f) : 0.0f;

  float4 s  = ((const float4*)(n_sum + (size_t)node * D))[lane];
  float4 xv = ((const float4*)(xt + (size_t)node * D))[lane];

  float h0 = s.x * inv + xv.x;
  float h1 = s.y * inv + xv.y;
  float h2 = s.z * inv + xv.z;
  float h3 = s.w * inv + xv.w;

  float sum = h0 + h1 + h2 + h3;
  float ss  = h0 * h0 + h1 * h1 + h2 * h2 + h3 * h3;
  #pragma unroll
  for (int o = 32; o > 0; o >>= 1) {
    sum += __shfl_xor(sum, o, 64);
    ss  += __shfl_xor(ss, o, 64);
  }
  float mu  = sum * (1.0f / D);
  float var = ss * (1.0f / D) - mu * mu;
  float rstd = rsqrtf(var + LN_EPS);

  float4 gv = ((const float4*)g)[lane];
  float4 bv = ((const float4*)b)[lane];

  float o0 = (h0 - mu) * rstd * gv.x + bv.x;
  float o1 = (h1 - mu) * rstd * gv.y + bv.y;
  float o2 = (h2 - mu) * rstd * gv.z + bv.z;
  float o3 = (h3 - mu) * rstd * gv.w + bv.w;
  o0 = o0 >= 0.f ? o0 : o0 * SLOPE;
  o1 = o1 >= 0.f ? o1 : o1 * SLOPE;
  o2 = o2 >= 0.f ? o2 : o2 * SLOPE;
  o3 = o3 >= 0.f ? o3 : o3 * SLOPE;

  if (add_res) {
    float4 rv = ((const float4*)(res + (size_t)node * D))[lane];
    o0 += rv.x; o1 += rv.y; o2 += rv.z; o3 += rv.w;
  }

  float4 ov = make_float4(o0, o1, o2, o3);
  ((float4*)(out + (size_t)node * D))[lane] = ov;
}

// ---------------------------------------------------------------------------
extern "C" void kernel_launch(void* const* d_in, const int* in_sizes, int n_in,
                              void* d_out, int out_size, void* d_ws, size_t ws_size,
                              hipStream_t stream) {
  const float* x       = (const float*)d_in[0];
  const float* node_W  = (const float*)d_in[1];  // [2,256,256]
  const float* node_b  = (const float*)d_in[2];  // [2,256]
  const float* he_W    = (const float*)d_in[3];
  const float* he_b    = (const float*)d_in[4];
  const float* ln_g    = (const float*)d_in[5];
  const float* ln_b    = (const float*)d_in[6];
  const float* hw      = (const float*)d_in[7];  // [25000]
  const int*   node_idx = (const int*)d_in[8];
  const int*   he_idx   = (const int*)d_in[9];
  float* out = (float*)d_out;

  // Workspace layout
  float* xt     = (float*)d_ws;                       // 100000*256
  float* n_sum  = xt + (size_t)N_NODES * D;           // 100000*256
  float* he_buf = n_sum + (size_t)N_NODES * D;        // 25000*256
  float* he_cnt = he_buf + (size_t)N_HE * D;          // 25000
  float* n_cnt  = he_cnt + N_HE;                      // 100000

  // Degree counts (identical for both layers)
  hipMemsetAsync(he_cnt, 0, (size_t)(N_HE + N_NODES) * sizeof(float), stream);
  count_kernel<<<(N_CONN + 255) / 256, 256, 0, stream>>>(node_idx, he_idx, he_cnt, n_cnt);

  for (int l = 0; l < 2; ++l) {
    const float* xin = (l == 0) ? x : out;
    const float* Wn = node_W + (size_t)l * D * D;
    const float* bn = node_b + (size_t)l * D;
    const float* We = he_W + (size_t)l * D * D;
    const float* be = he_b + (size_t)l * D;
    const float* g  = ln_g + (size_t)l * D;
    const float* bb = ln_b + (size_t)l * D;

    hipMemsetAsync(he_buf, 0, (size_t)N_HE * D * sizeof(float), stream);
    hipMemsetAsync(n_sum, 0, (size_t)N_NODES * D * sizeof(float), stream);

    gemm_node<<<(N_NODES + 31) / 32, 256, 0, stream>>>(xin, Wn, bn, xt, N_NODES);
    scatter_kernel<<<N_CONN / 4, 256, 0, stream>>>(xt, node_idx, he_idx, he_buf);
    gemm_he<<<(N_HE + 31) / 32, 256, 0, stream>>>(he_buf, We, be, hw, he_cnt, he_buf, N_HE);
    scatter_kernel<<<N_CONN / 4, 256, 0, stream>>>(he_buf, he_idx, node_idx, n_sum);
    finalize_kernel<<<N_NODES / 4, 256, 0, stream>>>(n_sum, n_cnt, xt, g, bb, xin, out, l);
  }
}

// Round 2
// 1212.986 us; speedup vs baseline: 5.2899x; 5.2899x over previous
//
#include <hip/hip_runtime.h>

#define D 256
#define N_NODES 100000
#define N_HE 25000
#define N_CONN 400000

constexpr float MEAN_EPS = 1e-8f;
constexpr float LN_EPS   = 1e-5f;
constexpr float SLOPE    = 0.2f;

// ---------------------------------------------------------------------------
// Degree histogram (indices are constant inputs; rebuilt every call)
// ---------------------------------------------------------------------------
__global__ __launch_bounds__(256) void hist_kernel(
    const int* __restrict__ node_idx, const int* __restrict__ he_idx,
    int* __restrict__ he_deg, int* __restrict__ n_deg) {
  int c = blockIdx.x * 256 + threadIdx.x;
  if (c < N_CONN) {
    atomicAdd(&he_deg[he_idx[c]], 1);
    atomicAdd(&n_deg[node_idx[c]], 1);
  }
}

// ---------------------------------------------------------------------------
// Segment allocation: start[i] = atomicAdd(total, deg[i]); cur[i] = start[i].
// Segment placement order is irrelevant (only contiguity matters).
// ---------------------------------------------------------------------------
__global__ __launch_bounds__(256) void alloc_kernel(
    const int* __restrict__ he_deg, const int* __restrict__ n_deg,
    int* __restrict__ totals,
    int* __restrict__ he_start, int* __restrict__ he_cur,
    int* __restrict__ n_start, int* __restrict__ n_cur) {
  int i = blockIdx.x * 256 + threadIdx.x;
  if (i < N_HE) {
    int s = atomicAdd(&totals[0], he_deg[i]);
    he_start[i] = s;
    he_cur[i] = s;
  }
  if (i < N_NODES) {
    int s = atomicAdd(&totals[1], n_deg[i]);
    n_start[i] = s;
    n_cur[i] = s;
  }
}

// ---------------------------------------------------------------------------
// Fill adjacency lists
// ---------------------------------------------------------------------------
__global__ __launch_bounds__(256) void fill_kernel(
    const int* __restrict__ node_idx, const int* __restrict__ he_idx,
    int* __restrict__ he_cur, int* __restrict__ n_cur,
    int* __restrict__ he_list, int* __restrict__ n_list) {
  int c = blockIdx.x * 256 + threadIdx.x;
  if (c < N_CONN) {
    int n = node_idx[c];
    int e = he_idx[c];
    int p = atomicAdd(&he_cur[e], 1);
    he_list[p] = n;
    int q = atomicAdd(&n_cur[n], 1);
    n_list[q] = e;
  }
}

// ---------------------------------------------------------------------------
// Node GEMM: out[r][c] = sum_k A[r][k] * W[k][c] + bias[c]
// 32 rows per block, 256 threads (1 col/thread), A tile staged in LDS.
// ---------------------------------------------------------------------------
__global__ __launch_bounds__(256) void gemm_node(
    const float* __restrict__ A, const float* __restrict__ W,
    const float* __restrict__ bias, float* __restrict__ out, int M) {
  __shared__ float As[32][D];
  const int t = threadIdx.x;
  const int row0 = blockIdx.x * 32;

  #pragma unroll 8
  for (int j = 0; j < 32; ++j) {
    int r = row0 + j;
    As[j][t] = (r < M) ? A[(size_t)r * D + t] : 0.f;
  }
  __syncthreads();

  float acc[32];
  #pragma unroll
  for (int r = 0; r < 32; ++r) acc[r] = 0.f;

  for (int k = 0; k < D; k += 4) {
    float w0 = W[(k + 0) * D + t];
    float w1 = W[(k + 1) * D + t];
    float w2 = W[(k + 2) * D + t];
    float w3 = W[(k + 3) * D + t];
    #pragma unroll
    for (int r = 0; r < 32; ++r) {
      float4 a = *(const float4*)&As[r][k];
      acc[r] = fmaf(a.x, w0, acc[r]);
      acc[r] = fmaf(a.y, w1, acc[r]);
      acc[r] = fmaf(a.z, w2, acc[r]);
      acc[r] = fmaf(a.w, w3, acc[r]);
    }
  }

  float b = bias[t];
  #pragma unroll 8
  for (int r = 0; r < 32; ++r) {
    int rr = row0 + r;
    if (rr < M) out[(size_t)rr * D + t] = acc[r] + b;
  }
}

// ---------------------------------------------------------------------------
// Hyperedge GEMM (in-place safe): out[r][c]=(sum_k A[r][k]*W[k][c]+be[c])*w[r]
// A rows already hold the MEAN of incident node features.
// ---------------------------------------------------------------------------
__global__ __launch_bounds__(256) void gemm_he(
    const float* __restrict__ A, const float* __restrict__ W,
    const float* __restrict__ bias, const float* __restrict__ hw,
    float* __restrict__ out, int M) {
  __shared__ float As[32][D];
  const int t = threadIdx.x;
  const int row0 = blockIdx.x * 32;

  #pragma unroll 8
  for (int j = 0; j < 32; ++j) {
    int r = row0 + j;
    As[j][t] = (r < M) ? A[(size_t)r * D + t] : 0.f;
  }
  __syncthreads();

  float acc[32];
  #pragma unroll
  for (int r = 0; r < 32; ++r) acc[r] = 0.f;

  for (int k = 0; k < D; k += 4) {
    float w0 = W[(k + 0) * D + t];
    float w1 = W[(k + 1) * D + t];
    float w2 = W[(k + 2) * D + t];
    float w3 = W[(k + 3) * D + t];
    #pragma unroll
    for (int r = 0; r < 32; ++r) {
      float4 a = *(const float4*)&As[r][k];
      acc[r] = fmaf(a.x, w0, acc[r]);
      acc[r] = fmaf(a.y, w1, acc[r]);
      acc[r] = fmaf(a.z, w2, acc[r]);
      acc[r] = fmaf(a.w, w3, acc[r]);
    }
  }

  float b = bias[t];
  #pragma unroll 8
  for (int r = 0; r < 32; ++r) {
    int rr = row0 + r;
    if (rr < M) out[(size_t)rr * D + t] = (acc[r] + b) * hw[rr];
  }
}

// ---------------------------------------------------------------------------
// Gather nodes -> hyperedge mean. One wave per hyperedge, float4/lane.
// ---------------------------------------------------------------------------
__global__ __launch_bounds__(256) void gather_he_kernel(
    const float* __restrict__ xt, const int* __restrict__ he_start,
    const int* __restrict__ he_deg, const int* __restrict__ he_list,
    float* __restrict__ he_out) {
  int e = blockIdx.x * 4 + (threadIdx.x >> 6);
  if (e >= N_HE) return;
  int lane = threadIdx.x & 63;
  int s = he_start[e];
  int deg = he_deg[e];

  float4 acc = make_float4(0.f, 0.f, 0.f, 0.f);
  for (int i = 0; i < deg; ++i) {
    int n = he_list[s + i];
    float4 v = ((const float4*)(xt + (size_t)n * D))[lane];
    acc.x += v.x; acc.y += v.y; acc.z += v.z; acc.w += v.w;
  }
  float inv = 1.0f / ((float)deg + MEAN_EPS);
  acc.x *= inv; acc.y *= inv; acc.z *= inv; acc.w *= inv;
  ((float4*)(he_out + (size_t)e * D))[lane] = acc;
}

// ---------------------------------------------------------------------------
// Fused: gather hyperedges -> node mean, + xt residual, LayerNorm, LeakyReLU,
// optional outer residual. One wave per node.
// ---------------------------------------------------------------------------
__global__ __launch_bounds__(256) void gather_node_finalize(
    const float* __restrict__ he_feat, const int* __restrict__ n_start,
    const int* __restrict__ n_deg, const int* __restrict__ n_list,
    const float* __restrict__ xt, const float* __restrict__ g,
    const float* __restrict__ b, const float* __restrict__ res,
    float* __restrict__ out, int add_res) {
  int node = blockIdx.x * 4 + (threadIdx.x >> 6);
  if (node >= N_NODES) return;
  int lane = threadIdx.x & 63;
  int s = n_start[node];
  int deg = n_deg[node];

  float4 acc = make_float4(0.f, 0.f, 0.f, 0.f);
  for (int i = 0; i < deg; ++i) {
    int e = n_list[s + i];
    float4 v = ((const float4*)(he_feat + (size_t)e * D))[lane];
    acc.x += v.x; acc.y += v.y; acc.z += v.z; acc.w += v.w;
  }
  float inv = deg > 0 ? 1.0f / (float)deg : 0.0f;

  float4 xv = ((const float4*)(xt + (size_t)node * D))[lane];
  float h0 = acc.x * inv + xv.x;
  float h1 = acc.y * inv + xv.y;
  float h2 = acc.z * inv + xv.z;
  float h3 = acc.w * inv + xv.w;

  float sum = h0 + h1 + h2 + h3;
  float ss  = h0 * h0 + h1 * h1 + h2 * h2 + h3 * h3;
  #pragma unroll
  for (int o = 32; o > 0; o >>= 1) {
    sum += __shfl_xor(sum, o, 64);
    ss  += __shfl_xor(ss, o, 64);
  }
  float mu  = sum * (1.0f / D);
  float var = ss * (1.0f / D) - mu * mu;
  float rstd = rsqrtf(var + LN_EPS);

  float4 gv = ((const float4*)g)[lane];
  float4 bv = ((const float4*)b)[lane];

  float o0 = (h0 - mu) * rstd * gv.x + bv.x;
  float o1 = (h1 - mu) * rstd * gv.y + bv.y;
  float o2 = (h2 - mu) * rstd * gv.z + bv.z;
  float o3 = (h3 - mu) * rstd * gv.w + bv.w;
  o0 = o0 >= 0.f ? o0 : o0 * SLOPE;
  o1 = o1 >= 0.f ? o1 : o1 * SLOPE;
  o2 = o2 >= 0.f ? o2 : o2 * SLOPE;
  o3 = o3 >= 0.f ? o3 : o3 * SLOPE;

  if (add_res) {
    float4 rv = ((const float4*)(res + (size_t)node * D))[lane];
    o0 += rv.x; o1 += rv.y; o2 += rv.z; o3 += rv.w;
  }

  ((float4*)(out + (size_t)node * D))[lane] = make_float4(o0, o1, o2, o3);
}

// ---------------------------------------------------------------------------
extern "C" void kernel_launch(void* const* d_in, const int* in_sizes, int n_in,
                              void* d_out, int out_size, void* d_ws, size_t ws_size,
                              hipStream_t stream) {
  const float* x       = (const float*)d_in[0];
  const float* node_W  = (const float*)d_in[1];  // [2,256,256]
  const float* node_b  = (const float*)d_in[2];  // [2,256]
  const float* he_W    = (const float*)d_in[3];
  const float* he_b    = (const float*)d_in[4];
  const float* ln_g    = (const float*)d_in[5];
  const float* ln_b    = (const float*)d_in[6];
  const float* hw      = (const float*)d_in[7];  // [25000]
  const int*   node_idx = (const int*)d_in[8];
  const int*   he_idx   = (const int*)d_in[9];
  float* out = (float*)d_out;

  // Workspace layout
  float* xt     = (float*)d_ws;                        // 100000*256 f32
  float* he_buf = xt + (size_t)N_NODES * D;            // 25000*256 f32
  int* he_deg   = (int*)(he_buf + (size_t)N_HE * D);   // 25000
  int* n_deg    = he_deg + N_HE;                       // 100000
  int* totals   = n_deg + N_NODES;                     // 2
  int* he_start = totals + 2;                          // 25000
  int* he_cur   = he_start + N_HE;                     // 25000
  int* n_start  = he_cur + N_HE;                       // 100000
  int* n_cur    = n_start + N_NODES;                   // 100000
  int* he_list  = n_cur + N_NODES;                     // 400000
  int* n_list   = he_list + N_CONN;                    // 400000

  // --- Build adjacency (every call; indices are constant inputs) ---
  hipMemsetAsync(he_deg, 0, (size_t)(N_HE + N_NODES + 2) * sizeof(int), stream);
  hist_kernel<<<(N_CONN + 255) / 256, 256, 0, stream>>>(node_idx, he_idx, he_deg, n_deg);
  alloc_kernel<<<(N_NODES + 255) / 256, 256, 0, stream>>>(
      he_deg, n_deg, totals, he_start, he_cur, n_start, n_cur);
  fill_kernel<<<(N_CONN + 255) / 256, 256, 0, stream>>>(
      node_idx, he_idx, he_cur, n_cur, he_list, n_list);

  for (int l = 0; l < 2; ++l) {
    const float* xin = (l == 0) ? x : out;
    const float* Wn = node_W + (size_t)l * D * D;
    const float* bn = node_b + (size_t)l * D;
    const float* We = he_W + (size_t)l * D * D;
    const float* be = he_b + (size_t)l * D;
    const float* g  = ln_g + (size_t)l * D;
    const float* bb = ln_b + (size_t)l * D;

    gemm_node<<<(N_NODES + 31) / 32, 256, 0, stream>>>(xin, Wn, bn, xt, N_NODES);
    gather_he_kernel<<<(N_HE + 3) / 4, 256, 0, stream>>>(
        xt, he_start, he_deg, he_list, he_buf);
    gemm_he<<<(N_HE + 31) / 32, 256, 0, stream>>>(he_buf, We, be, hw, he_buf, N_HE);
    gather_node_finalize<<<(N_NODES + 3) / 4, 256, 0, stream>>>(
        he_buf, n_start, n_deg, n_list, xt, g, bb, xin, out, l);
  }
}

// Round 3
// 848.200 us; speedup vs baseline: 7.5649x; 1.4301x over previous
//
#include <hip/hip_runtime.h>

#define D 256
#define N_NODES 100000
#define N_HE 25000
#define N_CONN 400000

constexpr float MEAN_EPS = 1e-8f;
constexpr float LN_EPS   = 1e-5f;
constexpr float SLOPE    = 0.2f;

typedef __attribute__((ext_vector_type(8))) short short8;
typedef __attribute__((ext_vector_type(4))) float f32x4;
typedef __attribute__((ext_vector_type(4))) unsigned short ushort4v;

static __device__ __forceinline__ unsigned short f2bf(float f) {
  unsigned int u = __builtin_bit_cast(unsigned int, f);
  u = (u + 0x7FFFu + ((u >> 16) & 1u)) >> 16;
  return (unsigned short)u;
}

// ---------------------------------------------------------------------------
// Degree histogram (indices are constant inputs; rebuilt every call)
// ---------------------------------------------------------------------------
__global__ __launch_bounds__(256) void hist_kernel(
    const int* __restrict__ node_idx, const int* __restrict__ he_idx,
    int* __restrict__ he_deg, int* __restrict__ n_deg) {
  int c = blockIdx.x * 256 + threadIdx.x;
  if (c < N_CONN) {
    atomicAdd(&he_deg[he_idx[c]], 1);
    atomicAdd(&n_deg[node_idx[c]], 1);
  }
}

__global__ __launch_bounds__(256) void alloc_kernel(
    const int* __restrict__ he_deg, const int* __restrict__ n_deg,
    int* __restrict__ totals,
    int* __restrict__ he_start, int* __restrict__ he_cur,
    int* __restrict__ n_start, int* __restrict__ n_cur) {
  int i = blockIdx.x * 256 + threadIdx.x;
  if (i < N_HE) {
    int s = atomicAdd(&totals[0], he_deg[i]);
    he_start[i] = s;
    he_cur[i] = s;
  }
  if (i < N_NODES) {
    int s = atomicAdd(&totals[1], n_deg[i]);
    n_start[i] = s;
    n_cur[i] = s;
  }
}

__global__ __launch_bounds__(256) void fill_kernel(
    const int* __restrict__ node_idx, const int* __restrict__ he_idx,
    int* __restrict__ he_cur, int* __restrict__ n_cur,
    int* __restrict__ he_list, int* __restrict__ n_list) {
  int c = blockIdx.x * 256 + threadIdx.x;
  if (c < N_CONN) {
    int n = node_idx[c];
    int e = he_idx[c];
    int p = atomicAdd(&he_cur[e], 1);
    he_list[p] = n;
    int q = atomicAdd(&n_cur[n], 1);
    n_list[q] = e;
  }
}

// ---------------------------------------------------------------------------
// Weight convert+transpose: Wt[n][k] = bf16(W[k][n]). One 64x64 tile/block.
// grid = nmat*16 blocks.
// ---------------------------------------------------------------------------
__global__ __launch_bounds__(256) void convert_w(
    const float* __restrict__ W, unsigned short* __restrict__ Wt) {
  int m = blockIdx.x >> 4;
  int tile = blockIdx.x & 15;
  int k0 = (tile >> 2) * 64, n0 = (tile & 3) * 64;
  const float* Win = W + (size_t)m * 65536;
  unsigned short* Wout = Wt + (size_t)m * 65536;
  __shared__ unsigned short T[64][65];
  int t = threadIdx.x;
  int r = t >> 6, c = t & 63;
  #pragma unroll 4
  for (int i = 0; i < 16; ++i) {
    int kr = i * 4 + r;
    T[kr][c] = f2bf(Win[(size_t)(k0 + kr) * 256 + n0 + c]);
  }
  __syncthreads();
  #pragma unroll 4
  for (int i = 0; i < 16; ++i) {
    int nr = i * 4 + r;
    Wout[(size_t)(n0 + nr) * 256 + k0 + c] = T[c][nr];
  }
}

// ---------------------------------------------------------------------------
// MFMA GEMM: out[r][c] = act(A[r][:] . W[:][c] + bias[c]) [* hw[r] if hw]
// A: fp32 [M][256]; Wt: bf16 [256 cols][256 k] (pre-transposed);
// 64 rows/block, 4 waves, each wave 16 rows x 256 cols.
// A staged fp32->bf16 in LDS with XOR swizzle (T2). In-place safe.
// ---------------------------------------------------------------------------
__global__ __launch_bounds__(256) void gemm_mfma(
    const float* __restrict__ A, const unsigned short* __restrict__ Wt,
    const float* __restrict__ bias, const float* __restrict__ hw,
    float* __restrict__ out, int M) {
  __shared__ unsigned short As[64 * 256];  // 32 KB
  const int t = threadIdx.x;
  const int row0 = blockIdx.x * 64;

  // ---- stage A tile (fp32 -> bf16, swizzled) ----
  #pragma unroll 4
  for (int i = 0; i < 16; ++i) {
    int row = i * 4 + (t >> 6);
    int col4 = t & 63;  // float4 index within row
    int r = row0 + row;
    float4 v = (r < M) ? ((const float4*)(A + (size_t)r * D))[col4]
                       : make_float4(0.f, 0.f, 0.f, 0.f);
    ushort4v o;
    o.x = f2bf(v.x); o.y = f2bf(v.y); o.z = f2bf(v.z); o.w = f2bf(v.w);
    unsigned int byte = (unsigned)(row * 512 + col4 * 8) ^ (unsigned)((row & 7) << 4);
    *(ushort4v*)((char*)As + byte) = o;
  }
  __syncthreads();

  const int wave = t >> 6, lane = t & 63;
  const int l15 = lane & 15, l4 = lane >> 4;

  f32x4 acc[16];
  #pragma unroll
  for (int n = 0; n < 16; ++n) acc[n] = (f32x4)0.f;

  const int arow = wave * 16 + l15;
  const unsigned int swz = (unsigned)((arow & 7) << 4);

  for (int kc = 0; kc < 8; ++kc) {
    unsigned int aaddr = (unsigned)(arow * 512 + kc * 64 + l4 * 16) ^ swz;
    short8 afrag = *(const short8*)((const char*)As + aaddr);
    const unsigned short* wp = Wt + (size_t)l15 * 256 + kc * 32 + l4 * 8;
    #pragma unroll
    for (int n = 0; n < 16; ++n) {
      short8 bfrag = *(const short8*)(wp + (size_t)n * 16 * 256);
      acc[n] = __builtin_amdgcn_mfma_f32_16x16x32_bf16(afrag, bfrag, acc[n], 0, 0, 0);
    }
  }

  // ---- epilogue ----
  const int orow = row0 + wave * 16 + l4 * 4;
  float w0 = 1.f, w1 = 1.f, w2 = 1.f, w3 = 1.f;
  if (hw) {
    w0 = (orow + 0 < M) ? hw[orow + 0] : 0.f;
    w1 = (orow + 1 < M) ? hw[orow + 1] : 0.f;
    w2 = (orow + 2 < M) ? hw[orow + 2] : 0.f;
    w3 = (orow + 3 < M) ? hw[orow + 3] : 0.f;
  }
  #pragma unroll
  for (int n = 0; n < 16; ++n) {
    int col = n * 16 + l15;
    float bb = bias[col];
    float v0 = (acc[n][0] + bb) * w0;
    float v1 = (acc[n][1] + bb) * w1;
    float v2 = (acc[n][2] + bb) * w2;
    float v3 = (acc[n][3] + bb) * w3;
    if (orow + 0 < M) out[(size_t)(orow + 0) * D + col] = v0;
    if (orow + 1 < M) out[(size_t)(orow + 1) * D + col] = v1;
    if (orow + 2 < M) out[(size_t)(orow + 2) * D + col] = v2;
    if (orow + 3 < M) out[(size_t)(orow + 3) * D + col] = v3;
  }
}

// ---------------------------------------------------------------------------
// Gather nodes -> hyperedge mean. One wave per hyperedge, float4/lane.
// ---------------------------------------------------------------------------
__global__ __launch_bounds__(256) void gather_he_kernel(
    const float* __restrict__ xt, const int* __restrict__ he_start,
    const int* __restrict__ he_deg, const int* __restrict__ he_list,
    float* __restrict__ he_out) {
  int e = blockIdx.x * 4 + (threadIdx.x >> 6);
  if (e >= N_HE) return;
  int lane = threadIdx.x & 63;
  int s = he_start[e];
  int deg = he_deg[e];

  float4 acc = make_float4(0.f, 0.f, 0.f, 0.f);
  for (int i = 0; i < deg; ++i) {
    int n = he_list[s + i];
    float4 v = ((const float4*)(xt + (size_t)n * D))[lane];
    acc.x += v.x; acc.y += v.y; acc.z += v.z; acc.w += v.w;
  }
  float inv = 1.0f / ((float)deg + MEAN_EPS);
  acc.x *= inv; acc.y *= inv; acc.z *= inv; acc.w *= inv;
  ((float4*)(he_out + (size_t)e * D))[lane] = acc;
}

// ---------------------------------------------------------------------------
// Fused: gather hyperedges -> node mean, + xt residual, LayerNorm, LeakyReLU,
// optional outer residual. One wave per node.
// ---------------------------------------------------------------------------
__global__ __launch_bounds__(256) void gather_node_finalize(
    const float* __restrict__ he_feat, const int* __restrict__ n_start,
    const int* __restrict__ n_deg, const int* __restrict__ n_list,
    const float* __restrict__ xt, const float* __restrict__ g,
    const float* __restrict__ b, const float* __restrict__ res,
    float* __restrict__ out, int add_res) {
  int node = blockIdx.x * 4 + (threadIdx.x >> 6);
  if (node >= N_NODES) return;
  int lane = threadIdx.x & 63;
  int s = n_start[node];
  int deg = n_deg[node];

  float4 acc = make_float4(0.f, 0.f, 0.f, 0.f);
  for (int i = 0; i < deg; ++i) {
    int e = n_list[s + i];
    float4 v = ((const float4*)(he_feat + (size_t)e * D))[lane];
    acc.x += v.x; acc.y += v.y; acc.z += v.z; acc.w += v.w;
  }
  float inv = deg > 0 ? 1.0f / (float)deg : 0.0f;

  float4 xv = ((const float4*)(xt + (size_t)node * D))[lane];
  float h0 = acc.x * inv + xv.x;
  float h1 = acc.y * inv + xv.y;
  float h2 = acc.z * inv + xv.z;
  float h3 = acc.w * inv + xv.w;

  float sum = h0 + h1 + h2 + h3;
  float ss  = h0 * h0 + h1 * h1 + h2 * h2 + h3 * h3;
  #pragma unroll
  for (int o = 32; o > 0; o >>= 1) {
    sum += __shfl_xor(sum, o, 64);
    ss  += __shfl_xor(ss, o, 64);
  }
  float mu  = sum * (1.0f / D);
  float var = ss * (1.0f / D) - mu * mu;
  float rstd = rsqrtf(var + LN_EPS);

  float4 gv = ((const float4*)g)[lane];
  float4 bv = ((const float4*)b)[lane];

  float o0 = (h0 - mu) * rstd * gv.x + bv.x;
  float o1 = (h1 - mu) * rstd * gv.y + bv.y;
  float o2 = (h2 - mu) * rstd * gv.z + bv.z;
  float o3 = (h3 - mu) * rstd * gv.w + bv.w;
  o0 = o0 >= 0.f ? o0 : o0 * SLOPE;
  o1 = o1 >= 0.f ? o1 : o1 * SLOPE;
  o2 = o2 >= 0.f ? o2 : o2 * SLOPE;
  o3 = o3 >= 0.f ? o3 : o3 * SLOPE;

  if (add_res) {
    float4 rv = ((const float4*)(res + (size_t)node * D))[lane];
    o0 += rv.x; o1 += rv.y; o2 += rv.z; o3 += rv.w;
  }

  ((float4*)(out + (size_t)node * D))[lane] = make_float4(o0, o1, o2, o3);
}

// ---------------------------------------------------------------------------
extern "C" void kernel_launch(void* const* d_in, const int* in_sizes, int n_in,
                              void* d_out, int out_size, void* d_ws, size_t ws_size,
                              hipStream_t stream) {
  const float* x       = (const float*)d_in[0];
  const float* node_W  = (const float*)d_in[1];  // [2,256,256]
  const float* node_b  = (const float*)d_in[2];  // [2,256]
  const float* he_W    = (const float*)d_in[3];
  const float* he_b    = (const float*)d_in[4];
  const float* ln_g    = (const float*)d_in[5];
  const float* ln_b    = (const float*)d_in[6];
  const float* hw      = (const float*)d_in[7];  // [25000]
  const int*   node_idx = (const int*)d_in[8];
  const int*   he_idx   = (const int*)d_in[9];
  float* out = (float*)d_out;

  // Workspace layout
  float* xt     = (float*)d_ws;                        // 100000*256 f32
  float* he_buf = xt + (size_t)N_NODES * D;            // 25000*256 f32
  unsigned short* Wt_node = (unsigned short*)(he_buf + (size_t)N_HE * D);  // 2*65536
  unsigned short* Wt_he   = Wt_node + 2 * 65536;       // 2*65536
  int* he_deg   = (int*)(Wt_he + 2 * 65536);           // 25000
  int* n_deg    = he_deg + N_HE;                       // 100000
  int* totals   = n_deg + N_NODES;                     // 2
  int* he_start = totals + 2;                          // 25000
  int* he_cur   = he_start + N_HE;                     // 25000
  int* n_start  = he_cur + N_HE;                       // 100000
  int* n_cur    = n_start + N_NODES;                   // 100000
  int* he_list  = n_cur + N_NODES;                     // 400000
  int* n_list   = he_list + N_CONN;                    // 400000

  // --- Weight convert+transpose (both layers) ---
  convert_w<<<32, 256, 0, stream>>>(node_W, Wt_node);
  convert_w<<<32, 256, 0, stream>>>(he_W, Wt_he);

  // --- Build adjacency (every call; indices are constant inputs) ---
  hipMemsetAsync(he_deg, 0, (size_t)(N_HE + N_NODES + 2) * sizeof(int), stream);
  hist_kernel<<<(N_CONN + 255) / 256, 256, 0, stream>>>(node_idx, he_idx, he_deg, n_deg);
  alloc_kernel<<<(N_NODES + 255) / 256, 256, 0, stream>>>(
      he_deg, n_deg, totals, he_start, he_cur, n_start, n_cur);
  fill_kernel<<<(N_CONN + 255) / 256, 256, 0, stream>>>(
      node_idx, he_idx, he_cur, n_cur, he_list, n_list);

  for (int l = 0; l < 2; ++l) {
    const float* xin = (l == 0) ? x : out;
    const float* bn = node_b + (size_t)l * D;
    const float* be = he_b + (size_t)l * D;
    const float* g  = ln_g + (size_t)l * D;
    const float* bb = ln_b + (size_t)l * D;

    gemm_mfma<<<(N_NODES + 63) / 64, 256, 0, stream>>>(
        xin, Wt_node + (size_t)l * 65536, bn, nullptr, xt, N_NODES);
    gather_he_kernel<<<(N_HE + 3) / 4, 256, 0, stream>>>(
        xt, he_start, he_deg, he_list, he_buf);
    gemm_mfma<<<(N_HE + 63) / 64, 256, 0, stream>>>(
        he_buf, Wt_he + (size_t)l * 65536, be, hw, he_buf, N_HE);
    gather_node_finalize<<<(N_NODES + 3) / 4, 256, 0, stream>>>(
        he_buf, n_start, n_deg, n_list, xt, g, bb, xin, out, l);
  }
}

// Round 4
// 626.706 us; speedup vs baseline: 10.2386x; 1.3534x over previous
//
#include <hip/hip_runtime.h>

#define D 256
#define N_NODES 100000
#define N_HE 25000
#define N_CONN 400000

constexpr float MEAN_EPS = 1e-8f;
constexpr float LN_EPS   = 1e-5f;
constexpr float SLOPE    = 0.2f;

typedef __attribute__((ext_vector_type(8))) short short8;
typedef __attribute__((ext_vector_type(4))) float f32x4;
typedef __attribute__((ext_vector_type(4))) unsigned short ushort4v;

static __device__ __forceinline__ unsigned short f2bf(float f) {
  unsigned int u = __builtin_bit_cast(unsigned int, f);
  u = (u + 0x7FFFu + ((u >> 16) & 1u)) >> 16;
  return (unsigned short)u;
}

// ---------------------------------------------------------------------------
// Degree histogram (indices are constant inputs; rebuilt every call)
// ---------------------------------------------------------------------------
__global__ __launch_bounds__(256) void hist_kernel(
    const int* __restrict__ node_idx, const int* __restrict__ he_idx,
    int* __restrict__ he_deg, int* __restrict__ n_deg) {
  int c = blockIdx.x * 256 + threadIdx.x;
  if (c < N_CONN) {
    atomicAdd(&he_deg[he_idx[c]], 1);
    atomicAdd(&n_deg[node_idx[c]], 1);
  }
}

__global__ __launch_bounds__(256) void alloc_kernel(
    const int* __restrict__ he_deg, const int* __restrict__ n_deg,
    int* __restrict__ totals,
    int* __restrict__ he_start, int* __restrict__ he_cur,
    int* __restrict__ n_start, int* __restrict__ n_cur) {
  int i = blockIdx.x * 256 + threadIdx.x;
  if (i < N_HE) {
    int s = atomicAdd(&totals[0], he_deg[i]);
    he_start[i] = s;
    he_cur[i] = s;
  }
  if (i < N_NODES) {
    int s = atomicAdd(&totals[1], n_deg[i]);
    n_start[i] = s;
    n_cur[i] = s;
  }
}

__global__ __launch_bounds__(256) void fill_kernel(
    const int* __restrict__ node_idx, const int* __restrict__ he_idx,
    int* __restrict__ he_cur, int* __restrict__ n_cur,
    int* __restrict__ he_list, int* __restrict__ n_list) {
  int c = blockIdx.x * 256 + threadIdx.x;
  if (c < N_CONN) {
    int n = node_idx[c];
    int e = he_idx[c];
    int p = atomicAdd(&he_cur[e], 1);
    he_list[p] = n;
    int q = atomicAdd(&n_cur[n], 1);
    n_list[q] = e;
  }
}

// ---------------------------------------------------------------------------
// Weight convert+transpose: Wt[n][k] = bf16(W[k][n]). One 64x64 tile/block.
// ---------------------------------------------------------------------------
__global__ __launch_bounds__(256) void convert_w(
    const float* __restrict__ W, unsigned short* __restrict__ Wt) {
  int m = blockIdx.x >> 4;
  int tile = blockIdx.x & 15;
  int k0 = (tile >> 2) * 64, n0 = (tile & 3) * 64;
  const float* Win = W + (size_t)m * 65536;
  unsigned short* Wout = Wt + (size_t)m * 65536;
  __shared__ unsigned short T[64][65];
  int t = threadIdx.x;
  int r = t >> 6, c = t & 63;
  #pragma unroll 4
  for (int i = 0; i < 16; ++i) {
    int kr = i * 4 + r;
    T[kr][c] = f2bf(Win[(size_t)(k0 + kr) * 256 + n0 + c]);
  }
  __syncthreads();
  #pragma unroll 4
  for (int i = 0; i < 16; ++i) {
    int nr = i * 4 + r;
    Wout[(size_t)(n0 + nr) * 256 + k0 + c] = T[c][nr];
  }
}

// ---------------------------------------------------------------------------
// Weight-stationary MFMA GEMM.
// out[r][c] = (A[r][:].W[:][c] + bias[c]) [* hw[r] if hw]
// Each wave owns a 64-col slice; its full B operand (64 cols x 256 k) lives
// in 128 VGPRs (statically indexed). Blocks grid-stride over 64-row tiles:
// stage A fp32->bf16 into XOR-swizzled LDS, then pure ds_read+MFMA.
// In-place safe: a tile is staged entirely before its rows are written, and
// only its own block touches those rows.
// ---------------------------------------------------------------------------
__global__ __launch_bounds__(256, 2) void gemm_ws(
    const float* __restrict__ A, const unsigned short* __restrict__ Wt,
    const float* __restrict__ bias, const float* __restrict__ hw,
    float* __restrict__ out, int M, int ntiles) {
  const int t = threadIdx.x;
  const int wave = t >> 6, lane = t & 63;
  const int l15 = lane & 15, l4 = lane >> 4;
  const int n0 = wave * 64;

  // ---- preload B fragments (persistent across tiles) ----
  short8 B[4][8];
  #pragma unroll
  for (int ct = 0; ct < 4; ++ct) {
    const unsigned short* bp = Wt + (size_t)(n0 + ct * 16 + l15) * 256 + l4 * 8;
    #pragma unroll
    for (int kc = 0; kc < 8; ++kc)
      B[ct][kc] = *(const short8*)(bp + kc * 32);
  }
  float bias_r[4];
  #pragma unroll
  for (int ct = 0; ct < 4; ++ct) bias_r[ct] = bias[n0 + ct * 16 + l15];

  __shared__ unsigned short As[64 * 256];  // 32 KB

  for (int tile = blockIdx.x; tile < ntiles; tile += gridDim.x) {
    const int row0 = tile * 64;

    // ---- stage A tile (fp32 -> bf16, XOR swizzle) ----
    #pragma unroll 4
    for (int i = 0; i < 16; ++i) {
      int row = i * 4 + wave;
      int col4 = lane;  // NOTE: col4 must span 0..63 -> use full thread id
      // (recompute from t to keep 64 threads covering a 1KB row)
      row = i * 4 + (t >> 6);
      col4 = t & 63;
      int r = row0 + row;
      float4 v = (r < M) ? ((const float4*)(A + (size_t)r * D))[col4]
                         : make_float4(0.f, 0.f, 0.f, 0.f);
      ushort4v o;
      o.x = f2bf(v.x); o.y = f2bf(v.y); o.z = f2bf(v.z); o.w = f2bf(v.w);
      unsigned int byte = (unsigned)(row * 512 + col4 * 8) ^ (unsigned)((row & 7) << 4);
      *(ushort4v*)((char*)As + byte) = o;
    }
    __syncthreads();

    #pragma unroll
    for (int rt = 0; rt < 4; ++rt) {
      const int arow = rt * 16 + l15;
      const unsigned int swz = (unsigned)((arow & 7) << 4);
      short8 a[8];
      #pragma unroll
      for (int kc = 0; kc < 8; ++kc) {
        unsigned int ad = (unsigned)(arow * 512 + kc * 64 + l4 * 16) ^ swz;
        a[kc] = *(const short8*)((const char*)As + ad);
      }
      f32x4 acc[4];
      #pragma unroll
      for (int ct = 0; ct < 4; ++ct) acc[ct] = (f32x4)0.f;
      #pragma unroll
      for (int kc = 0; kc < 8; ++kc) {
        #pragma unroll
        for (int ct = 0; ct < 4; ++ct)
          acc[ct] = __builtin_amdgcn_mfma_f32_16x16x32_bf16(a[kc], B[ct][kc], acc[ct], 0, 0, 0);
      }

      const int orow = row0 + rt * 16 + l4 * 4;
      float w0 = 1.f, w1 = 1.f, w2 = 1.f, w3 = 1.f;
      if (hw) {
        w0 = (orow + 0 < M) ? hw[orow + 0] : 0.f;
        w1 = (orow + 1 < M) ? hw[orow + 1] : 0.f;
        w2 = (orow + 2 < M) ? hw[orow + 2] : 0.f;
        w3 = (orow + 3 < M) ? hw[orow + 3] : 0.f;
      }
      #pragma unroll
      for (int ct = 0; ct < 4; ++ct) {
        int col = n0 + ct * 16 + l15;
        float bb = bias_r[ct];
        float v0 = (acc[ct][0] + bb) * w0;
        float v1 = (acc[ct][1] + bb) * w1;
        float v2 = (acc[ct][2] + bb) * w2;
        float v3 = (acc[ct][3] + bb) * w3;
        if (orow + 0 < M) out[(size_t)(orow + 0) * D + col] = v0;
        if (orow + 1 < M) out[(size_t)(orow + 1) * D + col] = v1;
        if (orow + 2 < M) out[(size_t)(orow + 2) * D + col] = v2;
        if (orow + 3 < M) out[(size_t)(orow + 3) * D + col] = v3;
      }
    }
    __syncthreads();  // protect As before next stage
  }
}

// ---------------------------------------------------------------------------
// Gather nodes -> hyperedge mean. One wave per hyperedge, float4/lane.
// ---------------------------------------------------------------------------
__global__ __launch_bounds__(256) void gather_he_kernel(
    const float* __restrict__ xt, const int* __restrict__ he_start,
    const int* __restrict__ he_deg, const int* __restrict__ he_list,
    float* __restrict__ he_out) {
  int e = blockIdx.x * 4 + (threadIdx.x >> 6);
  if (e >= N_HE) return;
  int lane = threadIdx.x & 63;
  int s = he_start[e];
  int deg = he_deg[e];

  float4 acc = make_float4(0.f, 0.f, 0.f, 0.f);
  for (int i = 0; i < deg; ++i) {
    int n = he_list[s + i];
    float4 v = ((const float4*)(xt + (size_t)n * D))[lane];
    acc.x += v.x; acc.y += v.y; acc.z += v.z; acc.w += v.w;
  }
  float inv = 1.0f / ((float)deg + MEAN_EPS);
  acc.x *= inv; acc.y *= inv; acc.z *= inv; acc.w *= inv;
  ((float4*)(he_out + (size_t)e * D))[lane] = acc;
}

// ---------------------------------------------------------------------------
// Fused: gather hyperedges -> node mean, + xt residual, LayerNorm, LeakyReLU,
// optional outer residual. One wave per node.
// ---------------------------------------------------------------------------
__global__ __launch_bounds__(256) void gather_node_finalize(
    const float* __restrict__ he_feat, const int* __restrict__ n_start,
    const int* __restrict__ n_deg, const int* __restrict__ n_list,
    const float* __restrict__ xt, const float* __restrict__ g,
    const float* __restrict__ b, const float* __restrict__ res,
    float* __restrict__ out, int add_res) {
  int node = blockIdx.x * 4 + (threadIdx.x >> 6);
  if (node >= N_NODES) return;
  int lane = threadIdx.x & 63;
  int s = n_start[node];
  int deg = n_deg[node];

  float4 acc = make_float4(0.f, 0.f, 0.f, 0.f);
  for (int i = 0; i < deg; ++i) {
    int e = n_list[s + i];
    float4 v = ((const float4*)(he_feat + (size_t)e * D))[lane];
    acc.x += v.x; acc.y += v.y; acc.z += v.z; acc.w += v.w;
  }
  float inv = deg > 0 ? 1.0f / (float)deg : 0.0f;

  float4 xv = ((const float4*)(xt + (size_t)node * D))[lane];
  float h0 = acc.x * inv + xv.x;
  float h1 = acc.y * inv + xv.y;
  float h2 = acc.z * inv + xv.z;
  float h3 = acc.w * inv + xv.w;

  float sum = h0 + h1 + h2 + h3;
  float ss  = h0 * h0 + h1 * h1 + h2 * h2 + h3 * h3;
  #pragma unroll
  for (int o = 32; o > 0; o >>= 1) {
    sum += __shfl_xor(sum, o, 64);
    ss  += __shfl_xor(ss, o, 64);
  }
  float mu  = sum * (1.0f / D);
  float var = ss * (1.0f / D) - mu * mu;
  float rstd = rsqrtf(var + LN_EPS);

  float4 gv = ((const float4*)g)[lane];
  float4 bv = ((const float4*)b)[lane];

  float o0 = (h0 - mu) * rstd * gv.x + bv.x;
  float o1 = (h1 - mu) * rstd * gv.y + bv.y;
  float o2 = (h2 - mu) * rstd * gv.z + bv.z;
  float o3 = (h3 - mu) * rstd * gv.w + bv.w;
  o0 = o0 >= 0.f ? o0 : o0 * SLOPE;
  o1 = o1 >= 0.f ? o1 : o1 * SLOPE;
  o2 = o2 >= 0.f ? o2 : o2 * SLOPE;
  o3 = o3 >= 0.f ? o3 : o3 * SLOPE;

  if (add_res) {
    float4 rv = ((const float4*)(res + (size_t)node * D))[lane];
    o0 += rv.x; o1 += rv.y; o2 += rv.z; o3 += rv.w;
  }

  ((float4*)(out + (size_t)node * D))[lane] = make_float4(o0, o1, o2, o3);
}

// ---------------------------------------------------------------------------
extern "C" void kernel_launch(void* const* d_in, const int* in_sizes, int n_in,
                              void* d_out, int out_size, void* d_ws, size_t ws_size,
                              hipStream_t stream) {
  const float* x       = (const float*)d_in[0];
  const float* node_W  = (const float*)d_in[1];  // [2,256,256]
  const float* node_b  = (const float*)d_in[2];  // [2,256]
  const float* he_W    = (const float*)d_in[3];
  const float* he_b    = (const float*)d_in[4];
  const float* ln_g    = (const float*)d_in[5];
  const float* ln_b    = (const float*)d_in[6];
  const float* hw      = (const float*)d_in[7];  // [25000]
  const int*   node_idx = (const int*)d_in[8];
  const int*   he_idx   = (const int*)d_in[9];
  float* out = (float*)d_out;

  // Workspace layout
  float* xt     = (float*)d_ws;                        // 100000*256 f32
  float* he_buf = xt + (size_t)N_NODES * D;            // 25000*256 f32
  unsigned short* Wt_node = (unsigned short*)(he_buf + (size_t)N_HE * D);  // 2*65536
  unsigned short* Wt_he   = Wt_node + 2 * 65536;       // 2*65536
  int* he_deg   = (int*)(Wt_he + 2 * 65536);           // 25000
  int* n_deg    = he_deg + N_HE;                       // 100000
  int* totals   = n_deg + N_NODES;                     // 2
  int* he_start = totals + 2;                          // 25000
  int* he_cur   = he_start + N_HE;                     // 25000
  int* n_start  = he_cur + N_HE;                       // 100000
  int* n_cur    = n_start + N_NODES;                   // 100000
  int* he_list  = n_cur + N_NODES;                     // 400000
  int* n_list   = he_list + N_CONN;                    // 400000

  // --- Weight convert+transpose (both layers) ---
  convert_w<<<32, 256, 0, stream>>>(node_W, Wt_node);
  convert_w<<<32, 256, 0, stream>>>(he_W, Wt_he);

  // --- Build adjacency (every call; indices are constant inputs) ---
  hipMemsetAsync(he_deg, 0, (size_t)(N_HE + N_NODES + 2) * sizeof(int), stream);
  hist_kernel<<<(N_CONN + 255) / 256, 256, 0, stream>>>(node_idx, he_idx, he_deg, n_deg);
  alloc_kernel<<<(N_NODES + 255) / 256, 256, 0, stream>>>(
      he_deg, n_deg, totals, he_start, he_cur, n_start, n_cur);
  fill_kernel<<<(N_CONN + 255) / 256, 256, 0, stream>>>(
      node_idx, he_idx, he_cur, n_cur, he_list, n_list);

  const int ntiles_node = (N_NODES + 63) / 64;  // 1563
  const int ntiles_he   = (N_HE + 63) / 64;     // 391

  for (int l = 0; l < 2; ++l) {
    const float* xin = (l == 0) ? x : out;
    const float* bn = node_b + (size_t)l * D;
    const float* be = he_b + (size_t)l * D;
    const float* g  = ln_g + (size_t)l * D;
    const float* bb = ln_b + (size_t)l * D;

    gemm_ws<<<512, 256, 0, stream>>>(
        xin, Wt_node + (size_t)l * 65536, bn, nullptr, xt, N_NODES, ntiles_node);
    gather_he_kernel<<<(N_HE + 3) / 4, 256, 0, stream>>>(
        xt, he_start, he_deg, he_list, he_buf);
    gemm_ws<<<ntiles_he, 256, 0, stream>>>(
        he_buf, Wt_he + (size_t)l * 65536, be, hw, he_buf, N_HE, ntiles_he);
    gather_node_finalize<<<(N_NODES + 3) / 4, 256, 0, stream>>>(
        he_buf, n_start, n_deg, n_list, xt, g, bb, xin, out, l);
  }
}

// Round 5
// 594.012 us; speedup vs baseline: 10.8021x; 1.0550x over previous
//
#include <hip/hip_runtime.h>

#define D 256
#define N_NODES 100000
#define N_HE 25000
#define N_CONN 400000

constexpr float MEAN_EPS = 1e-8f;
constexpr float LN_EPS   = 1e-5f;
constexpr float SLOPE    = 0.2f;

typedef __attribute__((ext_vector_type(8))) short short8;
typedef __attribute__((ext_vector_type(4))) float f32x4;
typedef __attribute__((ext_vector_type(4))) unsigned short ushort4v;

static __device__ __forceinline__ unsigned short f2bf(float f) {
  unsigned int u = __builtin_bit_cast(unsigned int, f);
  u = (u + 0x7FFFu + ((u >> 16) & 1u)) >> 16;
  return (unsigned short)u;
}
static __device__ __forceinline__ float bf2f(unsigned short u) {
  return __builtin_bit_cast(float, (unsigned int)u << 16);
}

// ---------------------------------------------------------------------------
// Adjacency build (indices are constant inputs; rebuilt every call)
// ---------------------------------------------------------------------------
__global__ __launch_bounds__(256) void hist_kernel(
    const int* __restrict__ node_idx, const int* __restrict__ he_idx,
    int* __restrict__ he_deg, int* __restrict__ n_deg) {
  int c = blockIdx.x * 256 + threadIdx.x;
  if (c < N_CONN) {
    atomicAdd(&he_deg[he_idx[c]], 1);
    atomicAdd(&n_deg[node_idx[c]], 1);
  }
}

__global__ __launch_bounds__(256) void alloc_kernel(
    const int* __restrict__ he_deg, const int* __restrict__ n_deg,
    int* __restrict__ totals,
    int* __restrict__ he_start, int* __restrict__ he_cur,
    int* __restrict__ n_start, int* __restrict__ n_cur) {
  int i = blockIdx.x * 256 + threadIdx.x;
  if (i < N_HE) {
    int s = atomicAdd(&totals[0], he_deg[i]);
    he_start[i] = s;
    he_cur[i] = s;
  }
  if (i < N_NODES) {
    int s = atomicAdd(&totals[1], n_deg[i]);
    n_start[i] = s;
    n_cur[i] = s;
  }
}

__global__ __launch_bounds__(256) void fill_kernel(
    const int* __restrict__ node_idx, const int* __restrict__ he_idx,
    int* __restrict__ he_cur, int* __restrict__ n_cur,
    int* __restrict__ he_list, int* __restrict__ n_list) {
  int c = blockIdx.x * 256 + threadIdx.x;
  if (c < N_CONN) {
    int n = node_idx[c];
    int e = he_idx[c];
    int p = atomicAdd(&he_cur[e], 1);
    he_list[p] = n;
    int q = atomicAdd(&n_cur[n], 1);
    n_list[q] = e;
  }
}

// ---------------------------------------------------------------------------
// Weight convert+transpose: Wt[n][k] = bf16(W[k][n]). One 64x64 tile/block.
// ---------------------------------------------------------------------------
__global__ __launch_bounds__(256) void convert_w(
    const float* __restrict__ W, unsigned short* __restrict__ Wt) {
  int m = blockIdx.x >> 4;
  int tile = blockIdx.x & 15;
  int k0 = (tile >> 2) * 64, n0 = (tile & 3) * 64;
  const float* Win = W + (size_t)m * 65536;
  unsigned short* Wout = Wt + (size_t)m * 65536;
  __shared__ unsigned short T[64][65];
  int t = threadIdx.x;
  int r = t >> 6, c = t & 63;
  #pragma unroll 4
  for (int i = 0; i < 16; ++i) {
    int kr = i * 4 + r;
    T[kr][c] = f2bf(Win[(size_t)(k0 + kr) * 256 + n0 + c]);
  }
  __syncthreads();
  #pragma unroll 4
  for (int i = 0; i < 16; ++i) {
    int nr = i * 4 + r;
    Wout[(size_t)(n0 + nr) * 256 + k0 + c] = T[c][nr];
  }
}

// ---------------------------------------------------------------------------
// MFMA GEMM, B-in-LDS, one 64-row tile per block.
// out[r][c] = (A[r][:].W[:][c] + bias[c]) [* hw[r] if hw]
// A (fp32 or bf16) staged bf16+swizzled in As (32KB). B staged per 64-col
// group in Bs (32KB, same involutive swizzle). acc for all 256 cols held in
// VGPRs across the col-group loop; single epilogue. In-place safe (A fully
// staged before any store; block-private rows).
// ---------------------------------------------------------------------------
template <int A_F32, int O_F32>
__global__ __launch_bounds__(256, 2) void gemm_tile(
    const void* __restrict__ Ain, const unsigned short* __restrict__ Wt,
    const float* __restrict__ bias, const float* __restrict__ hw,
    void* __restrict__ outv, int M) {
  __shared__ unsigned short As[64 * 256];  // 32 KB
  __shared__ unsigned short Bs[64 * 256];  // 32 KB (64 cols x 256 k)
  const int t = threadIdx.x;
  const int wave = t >> 6, lane = t & 63;
  const int l15 = lane & 15, l4 = lane >> 4;
  const int row0 = blockIdx.x * 64;

  // ---- stage A tile (-> bf16, XOR swizzle) ----
  if (A_F32) {
    const float* A = (const float*)Ain;
    #pragma unroll 4
    for (int i = 0; i < 16; ++i) {
      int row = i * 4 + (t >> 6);
      int col4 = t & 63;
      int r = row0 + row;
      float4 v = (r < M) ? ((const float4*)(A + (size_t)r * D))[col4]
                         : make_float4(0.f, 0.f, 0.f, 0.f);
      ushort4v o;
      o[0] = f2bf(v.x); o[1] = f2bf(v.y); o[2] = f2bf(v.z); o[3] = f2bf(v.w);
      unsigned int byte = (unsigned)(row * 512 + col4 * 8) ^ (unsigned)((row & 7) << 4);
      *(ushort4v*)((char*)As + byte) = o;
    }
  } else {
    const unsigned short* A = (const unsigned short*)Ain;
    #pragma unroll 4
    for (int i = 0; i < 8; ++i) {
      int row = i * 8 + (t >> 5);
      int e = t & 31;
      int r = row0 + row;
      short8 v = {};
      if (r < M) v = *(const short8*)(A + (size_t)r * D + e * 8);
      unsigned int byte = (unsigned)(row * 512 + e * 16) ^ (unsigned)((row & 7) << 4);
      *(short8*)((char*)As + byte) = v;
    }
  }

  // ---- stage B col-group 0 ----
  {
    const char* Wcg = (const char*)Wt;  // cg 0
    #pragma unroll 4
    for (int j = 0; j < 8; ++j) {
      unsigned int o = (unsigned)(j * 4096 + t * 16);
      short8 v = *(const short8*)(Wcg + o);
      unsigned int b = o ^ (unsigned)(((o >> 9) & 7) << 4);
      *(short8*)((char*)Bs + b) = v;
    }
  }
  __syncthreads();

  // ---- A fragments (this wave's 16 rows), reused across all col groups ----
  const int arow = wave * 16 + l15;
  const unsigned int aswz = (unsigned)((arow & 7) << 4);
  short8 a[8];
  #pragma unroll
  for (int kc = 0; kc < 8; ++kc) {
    unsigned int ad = (unsigned)(arow * 512 + kc * 64 + l4 * 16) ^ aswz;
    a[kc] = *(const short8*)((const char*)As + ad);
  }

  f32x4 acc[16];
  #pragma unroll
  for (int i = 0; i < 16; ++i) acc[i] = (f32x4)0.f;

  #pragma unroll
  for (int cg = 0; cg < 4; ++cg) {
    // compute this col group (64 cols): 32 ds_read_b128 + 32 MFMA per wave
    #pragma unroll
    for (int kc = 0; kc < 8; ++kc) {
      #pragma unroll
      for (int ct = 0; ct < 4; ++ct) {
        int c = ct * 16 + l15;
        unsigned int bd = (unsigned)(c * 512 + kc * 64 + l4 * 16) ^ (unsigned)((c & 7) << 4);
        short8 bf = *(const short8*)((const char*)Bs + bd);
        acc[cg * 4 + ct] = __builtin_amdgcn_mfma_f32_16x16x32_bf16(a[kc], bf, acc[cg * 4 + ct], 0, 0, 0);
      }
    }
    if (cg < 3) {
      __syncthreads();  // everyone done reading Bs
      const char* Wcg = (const char*)(Wt + (size_t)(cg + 1) * 64 * 256);
      #pragma unroll 4
      for (int j = 0; j < 8; ++j) {
        unsigned int o = (unsigned)(j * 4096 + t * 16);
        short8 v = *(const short8*)(Wcg + o);
        unsigned int b = o ^ (unsigned)(((o >> 9) & 7) << 4);
        *(short8*)((char*)Bs + b) = v;
      }
      __syncthreads();  // next group staged
    }
  }

  // ---- epilogue ----
  const int orow = row0 + wave * 16 + l4 * 4;
  float w0 = 1.f, w1 = 1.f, w2 = 1.f, w3 = 1.f;
  if (hw) {
    w0 = (orow + 0 < M) ? hw[orow + 0] : 0.f;
    w1 = (orow + 1 < M) ? hw[orow + 1] : 0.f;
    w2 = (orow + 2 < M) ? hw[orow + 2] : 0.f;
    w3 = (orow + 3 < M) ? hw[orow + 3] : 0.f;
  }
  #pragma unroll
  for (int cg = 0; cg < 4; ++cg) {
    #pragma unroll
    for (int ct = 0; ct < 4; ++ct) {
      int col = cg * 64 + ct * 16 + l15;
      float bb = bias[col];
      f32x4 v = acc[cg * 4 + ct];
      float r0 = (v[0] + bb) * w0;
      float r1 = (v[1] + bb) * w1;
      float r2 = (v[2] + bb) * w2;
      float r3 = (v[3] + bb) * w3;
      if (O_F32) {
        float* out = (float*)outv;
        if (orow + 0 < M) out[(size_t)(orow + 0) * D + col] = r0;
        if (orow + 1 < M) out[(size_t)(orow + 1) * D + col] = r1;
        if (orow + 2 < M) out[(size_t)(orow + 2) * D + col] = r2;
        if (orow + 3 < M) out[(size_t)(orow + 3) * D + col] = r3;
      } else {
        unsigned short* out = (unsigned short*)outv;
        if (orow + 0 < M) out[(size_t)(orow + 0) * D + col] = f2bf(r0);
        if (orow + 1 < M) out[(size_t)(orow + 1) * D + col] = f2bf(r1);
        if (orow + 2 < M) out[(size_t)(orow + 2) * D + col] = f2bf(r2);
        if (orow + 3 < M) out[(size_t)(orow + 3) * D + col] = f2bf(r3);
      }
    }
  }
}

// ---------------------------------------------------------------------------
// Gather nodes -> hyperedge mean (bf16 in, bf16 out). One wave per hyperedge.
// ---------------------------------------------------------------------------
__global__ __launch_bounds__(256) void gather_he_kernel(
    const unsigned short* __restrict__ xt, const int* __restrict__ he_start,
    const int* __restrict__ he_deg, const int* __restrict__ he_list,
    unsigned short* __restrict__ he_out) {
  int e = blockIdx.x * 4 + (threadIdx.x >> 6);
  if (e >= N_HE) return;
  int lane = threadIdx.x & 63;
  int s = he_start[e];
  int deg = he_deg[e];

  float a0 = 0.f, a1 = 0.f, a2 = 0.f, a3 = 0.f;
  for (int i = 0; i < deg; ++i) {
    int n = he_list[s + i];
    ushort4v v = ((const ushort4v*)(xt + (size_t)n * D))[lane];
    a0 += bf2f(v[0]); a1 += bf2f(v[1]); a2 += bf2f(v[2]); a3 += bf2f(v[3]);
  }
  float inv = 1.0f / ((float)deg + MEAN_EPS);
  ushort4v o;
  o[0] = f2bf(a0 * inv); o[1] = f2bf(a1 * inv);
  o[2] = f2bf(a2 * inv); o[3] = f2bf(a3 * inv);
  ((ushort4v*)(he_out + (size_t)e * D))[lane] = o;
}

// ---------------------------------------------------------------------------
// Fused: gather hyperedges -> node mean, + xt residual, LayerNorm, LeakyReLU,
// optional outer residual. One wave per node. bf16 gathers, f32 math/out.
// ---------------------------------------------------------------------------
__global__ __launch_bounds__(256) void gather_node_finalize(
    const unsigned short* __restrict__ he_feat, const int* __restrict__ n_start,
    const int* __restrict__ n_deg, const int* __restrict__ n_list,
    const unsigned short* __restrict__ xt, const float* __restrict__ g,
    const float* __restrict__ b, const float* __restrict__ res,
    float* __restrict__ out, int add_res) {
  int node = blockIdx.x * 4 + (threadIdx.x >> 6);
  if (node >= N_NODES) return;
  int lane = threadIdx.x & 63;
  int s = n_start[node];
  int deg = n_deg[node];

  float a0 = 0.f, a1 = 0.f, a2 = 0.f, a3 = 0.f;
  for (int i = 0; i < deg; ++i) {
    int e = n_list[s + i];
    ushort4v v = ((const ushort4v*)(he_feat + (size_t)e * D))[lane];
    a0 += bf2f(v[0]); a1 += bf2f(v[1]); a2 += bf2f(v[2]); a3 += bf2f(v[3]);
  }
  float inv = deg > 0 ? 1.0f / (float)deg : 0.0f;

  ushort4v xv = ((const ushort4v*)(xt + (size_t)node * D))[lane];
  float h0 = a0 * inv + bf2f(xv[0]);
  float h1 = a1 * inv + bf2f(xv[1]);
  float h2 = a2 * inv + bf2f(xv[2]);
  float h3 = a3 * inv + bf2f(xv[3]);

  float sum = h0 + h1 + h2 + h3;
  float ss  = h0 * h0 + h1 * h1 + h2 * h2 + h3 * h3;
  #pragma unroll
  for (int o = 32; o > 0; o >>= 1) {
    sum += __shfl_xor(sum, o, 64);
    ss  += __shfl_xor(ss, o, 64);
  }
  float mu  = sum * (1.0f / D);
  float var = ss * (1.0f / D) - mu * mu;
  float rstd = rsqrtf(var + LN_EPS);

  float4 gv = ((const float4*)g)[lane];
  float4 bv = ((const float4*)b)[lane];

  float o0 = (h0 - mu) * rstd * gv.x + bv.x;
  float o1 = (h1 - mu) * rstd * gv.y + bv.y;
  float o2 = (h2 - mu) * rstd * gv.z + bv.z;
  float o3 = (h3 - mu) * rstd * gv.w + bv.w;
  o0 = o0 >= 0.f ? o0 : o0 * SLOPE;
  o1 = o1 >= 0.f ? o1 : o1 * SLOPE;
  o2 = o2 >= 0.f ? o2 : o2 * SLOPE;
  o3 = o3 >= 0.f ? o3 : o3 * SLOPE;

  if (add_res) {
    float4 rv = ((const float4*)(res + (size_t)node * D))[lane];
    o0 += rv.x; o1 += rv.y; o2 += rv.z; o3 += rv.w;
  }

  ((float4*)(out + (size_t)node * D))[lane] = make_float4(o0, o1, o2, o3);
}

// ---------------------------------------------------------------------------
extern "C" void kernel_launch(void* const* d_in, const int* in_sizes, int n_in,
                              void* d_out, int out_size, void* d_ws, size_t ws_size,
                              hipStream_t stream) {
  const float* x       = (const float*)d_in[0];
  const float* node_W  = (const float*)d_in[1];  // [2,256,256]
  const float* node_b  = (const float*)d_in[2];  // [2,256]
  const float* he_W    = (const float*)d_in[3];
  const float* he_b    = (const float*)d_in[4];
  const float* ln_g    = (const float*)d_in[5];
  const float* ln_b    = (const float*)d_in[6];
  const float* hw      = (const float*)d_in[7];  // [25000]
  const int*   node_idx = (const int*)d_in[8];
  const int*   he_idx   = (const int*)d_in[9];
  float* out = (float*)d_out;

  // Workspace layout (bf16 intermediates)
  unsigned short* xt     = (unsigned short*)d_ws;           // 100000*256 bf16
  unsigned short* he_buf = xt + (size_t)N_NODES * D;        // 25000*256 bf16
  unsigned short* Wt_node = he_buf + (size_t)N_HE * D;      // 2*65536 bf16
  unsigned short* Wt_he   = Wt_node + 2 * 65536;            // 2*65536 bf16
  int* he_deg   = (int*)(Wt_he + 2 * 65536);                // 25000
  int* n_deg    = he_deg + N_HE;                            // 100000
  int* totals   = n_deg + N_NODES;                          // 2
  int* he_start = totals + 2;                               // 25000
  int* he_cur   = he_start + N_HE;                          // 25000
  int* n_start  = he_cur + N_HE;                            // 100000
  int* n_cur    = n_start + N_NODES;                        // 100000
  int* he_list  = n_cur + N_NODES;                          // 400000
  int* n_list   = he_list + N_CONN;                         // 400000

  // --- Weight convert+transpose (both layers) ---
  convert_w<<<32, 256, 0, stream>>>(node_W, Wt_node);
  convert_w<<<32, 256, 0, stream>>>(he_W, Wt_he);

  // --- Build adjacency (every call; indices are constant inputs) ---
  hipMemsetAsync(he_deg, 0, (size_t)(N_HE + N_NODES + 2) * sizeof(int), stream);
  hist_kernel<<<(N_CONN + 255) / 256, 256, 0, stream>>>(node_idx, he_idx, he_deg, n_deg);
  alloc_kernel<<<(N_NODES + 255) / 256, 256, 0, stream>>>(
      he_deg, n_deg, totals, he_start, he_cur, n_start, n_cur);
  fill_kernel<<<(N_CONN + 255) / 256, 256, 0, stream>>>(
      node_idx, he_idx, he_cur, n_cur, he_list, n_list);

  const int ntiles_node = (N_NODES + 63) / 64;  // 1563
  const int ntiles_he   = (N_HE + 63) / 64;     // 391

  for (int l = 0; l < 2; ++l) {
    const float* xin = (l == 0) ? x : out;
    const float* bn = node_b + (size_t)l * D;
    const float* be = he_b + (size_t)l * D;
    const float* g  = ln_g + (size_t)l * D;
    const float* bb = ln_b + (size_t)l * D;

    gemm_tile<1, 0><<<ntiles_node, 256, 0, stream>>>(
        xin, Wt_node + (size_t)l * 65536, bn, nullptr, xt, N_NODES);
    gather_he_kernel<<<(N_HE + 3) / 4, 256, 0, stream>>>(
        xt, he_start, he_deg, he_list, he_buf);
    gemm_tile<0, 0><<<ntiles_he, 256, 0, stream>>>(
        he_buf, Wt_he + (size_t)l * 65536, be, hw, he_buf, N_HE);
    gather_node_finalize<<<(N_NODES + 3) / 4, 256, 0, stream>>>(
        he_buf, n_start, n_deg, n_list, xt, g, bb, xin, out, l);
  }
}

// Round 6
// 473.815 us; speedup vs baseline: 13.5424x; 1.2537x over previous
//
#include <hip/hip_runtime.h>

#define D 256
#define N_NODES 100000
#define N_HE 25000
#define N_CONN 400000

constexpr float MEAN_EPS = 1e-8f;
constexpr float LN_EPS   = 1e-5f;
constexpr float SLOPE    = 0.2f;

typedef __attribute__((ext_vector_type(8))) short short8;
typedef __attribute__((ext_vector_type(4))) float f32x4;
typedef __attribute__((ext_vector_type(16))) float f32x16;
typedef __attribute__((ext_vector_type(4))) unsigned short ushort4v;

static __device__ __forceinline__ unsigned short f2bf(float f) {
  unsigned int u = __builtin_bit_cast(unsigned int, f);
  u = (u + 0x7FFFu + ((u >> 16) & 1u)) >> 16;
  return (unsigned short)u;
}
static __device__ __forceinline__ float bf2f(unsigned short u) {
  return __builtin_bit_cast(float, (unsigned int)u << 16);
}

// ---------------------------------------------------------------------------
// Adjacency build (indices are constant inputs; rebuilt every call)
// ---------------------------------------------------------------------------
__global__ __launch_bounds__(256) void hist_kernel(
    const int* __restrict__ node_idx, const int* __restrict__ he_idx,
    int* __restrict__ he_deg, int* __restrict__ n_deg) {
  int c = blockIdx.x * 256 + threadIdx.x;
  if (c < N_CONN) {
    atomicAdd(&he_deg[he_idx[c]], 1);
    atomicAdd(&n_deg[node_idx[c]], 1);
  }
}

__global__ __launch_bounds__(256) void alloc_kernel(
    const int* __restrict__ he_deg, const int* __restrict__ n_deg,
    int* __restrict__ totals,
    int* __restrict__ he_start, int* __restrict__ he_cur,
    int* __restrict__ n_start, int* __restrict__ n_cur) {
  int i = blockIdx.x * 256 + threadIdx.x;
  if (i < N_HE) {
    int s = atomicAdd(&totals[0], he_deg[i]);
    he_start[i] = s;
    he_cur[i] = s;
  }
  if (i < N_NODES) {
    int s = atomicAdd(&totals[1], n_deg[i]);
    n_start[i] = s;
    n_cur[i] = s;
  }
}

__global__ __launch_bounds__(256) void fill_kernel(
    const int* __restrict__ node_idx, const int* __restrict__ he_idx,
    int* __restrict__ he_cur, int* __restrict__ n_cur,
    int* __restrict__ he_list, int* __restrict__ n_list) {
  int c = blockIdx.x * 256 + threadIdx.x;
  if (c < N_CONN) {
    int n = node_idx[c];
    int e = he_idx[c];
    int p = atomicAdd(&he_cur[e], 1);
    he_list[p] = n;
    int q = atomicAdd(&n_cur[n], 1);
    n_list[q] = e;
  }
}

// ---------------------------------------------------------------------------
// Weight convert+transpose: Wt[n][k] = bf16(W[k][n]). One 64x64 tile/block.
// ---------------------------------------------------------------------------
__global__ __launch_bounds__(256) void convert_w(
    const float* __restrict__ W, unsigned short* __restrict__ Wt) {
  int m = blockIdx.x >> 4;
  int tile = blockIdx.x & 15;
  int k0 = (tile >> 2) * 64, n0 = (tile & 3) * 64;
  const float* Win = W + (size_t)m * 65536;
  unsigned short* Wout = Wt + (size_t)m * 65536;
  __shared__ unsigned short T[64][65];
  int t = threadIdx.x;
  int r = t >> 6, c = t & 63;
  #pragma unroll 4
  for (int i = 0; i < 16; ++i) {
    int kr = i * 4 + r;
    T[kr][c] = f2bf(Win[(size_t)(k0 + kr) * 256 + n0 + c]);
  }
  __syncthreads();
  #pragma unroll 4
  for (int i = 0; i < 16; ++i) {
    int nr = i * 4 + r;
    Wout[(size_t)(n0 + nr) * 256 + k0 + c] = T[c][nr];
  }
}

// ---------------------------------------------------------------------------
// 32x32x16 MFMA GEMM, weight-stationary-in-VGPR (asm-pinned).
// out[r][c] = (A[r][:].W[:][c] + bias[c]) [* hw[r] if hw]
// Block = 64 rows x 256 cols, 4 waves; wave owns 64 cols (2 col-tiles of 32).
// B: 2x16 fragments (128 VGPR), loaded once, pinned via asm so the register
// allocator cannot sink the loads into the tile loop. A staged bf16 in LDS
// with the involutive XOR swizzle (conflict-free reads). Grid-stride tiles.
// In-place safe (tile fully staged before stores; rows block-private).
// ---------------------------------------------------------------------------
template <int A_F32, int O_F32>
__global__ __launch_bounds__(256, 2) void gemm32(
    const void* __restrict__ Ain, const unsigned short* __restrict__ Wt,
    const float* __restrict__ bias, const float* __restrict__ hw,
    void* __restrict__ outv, int M, int ntiles) {
  __shared__ unsigned short As[64 * 256];  // 32 KB [row][k] bf16, swizzled
  const int t = threadIdx.x;
  const int wave = t >> 6, lane = t & 63;
  const int l31 = lane & 31, lhi = lane >> 5;
  const int colbase = wave * 64;

  // ---- preload + pin B fragments: B[ct][kc], lane l31 = col, lhi = k-half
  f32x4 B[2][16];
  #pragma unroll
  for (int ct = 0; ct < 2; ++ct) {
    const unsigned short* bp =
        Wt + (size_t)(colbase + ct * 32 + l31) * 256 + lhi * 8;
    #pragma unroll
    for (int kc = 0; kc < 16; ++kc)
      B[ct][kc] = *(const f32x4*)(bp + kc * 16);
  }
  #pragma unroll
  for (int ct = 0; ct < 2; ++ct)
    #pragma unroll
    for (int kc = 0; kc < 16; ++kc)
      asm volatile("" : "+v"(B[ct][kc]));

  float biasv[2];
  #pragma unroll
  for (int ct = 0; ct < 2; ++ct) biasv[ct] = bias[colbase + ct * 32 + l31];

  for (int tile = blockIdx.x; tile < ntiles; tile += gridDim.x) {
    const int row0 = tile * 64;

    // ---- stage A tile (-> bf16, XOR swizzle) ----
    if (A_F32) {
      const float* A = (const float*)Ain;
      #pragma unroll 4
      for (int i = 0; i < 16; ++i) {
        int row = i * 4 + (t >> 6);
        int col4 = t & 63;
        int r = row0 + row;
        float4 v = (r < M) ? ((const float4*)(A + (size_t)r * D))[col4]
                           : make_float4(0.f, 0.f, 0.f, 0.f);
        ushort4v o;
        o[0] = f2bf(v.x); o[1] = f2bf(v.y); o[2] = f2bf(v.z); o[3] = f2bf(v.w);
        unsigned int byte = (unsigned)(row * 512 + col4 * 8) ^ (unsigned)((row & 7) << 4);
        *(ushort4v*)((char*)As + byte) = o;
      }
    } else {
      const unsigned short* A = (const unsigned short*)Ain;
      #pragma unroll 4
      for (int i = 0; i < 8; ++i) {
        int row = i * 8 + (t >> 5);
        int e = t & 31;
        int r = row0 + row;
        short8 v = {};
        if (r < M) v = *(const short8*)(A + (size_t)r * D + e * 8);
        unsigned int byte = (unsigned)(row * 512 + e * 16) ^ (unsigned)((row & 7) << 4);
        *(short8*)((char*)As + byte) = v;
      }
    }
    __syncthreads();

    // ---- 16 k-steps: 2 ds_read_b128 + 4 MFMA each ----
    f32x16 acc00 = (f32x16)0.f, acc01 = (f32x16)0.f;
    f32x16 acc10 = (f32x16)0.f, acc11 = (f32x16)0.f;
    #pragma unroll
    for (int kc = 0; kc < 16; ++kc) {
      int r0 = l31;
      unsigned int ad0 = (unsigned)(r0 * 512 + kc * 32 + lhi * 16) ^ (unsigned)((r0 & 7) << 4);
      short8 a0 = *(const short8*)((const char*)As + ad0);
      int r1 = 32 + l31;
      unsigned int ad1 = (unsigned)(r1 * 512 + kc * 32 + lhi * 16) ^ (unsigned)((r1 & 7) << 4);
      short8 a1 = *(const short8*)((const char*)As + ad1);
      short8 b0 = __builtin_bit_cast(short8, B[0][kc]);
      short8 b1 = __builtin_bit_cast(short8, B[1][kc]);
      acc00 = __builtin_amdgcn_mfma_f32_32x32x16_bf16(a0, b0, acc00, 0, 0, 0);
      acc01 = __builtin_amdgcn_mfma_f32_32x32x16_bf16(a0, b1, acc01, 0, 0, 0);
      acc10 = __builtin_amdgcn_mfma_f32_32x32x16_bf16(a1, b0, acc10, 0, 0, 0);
      acc11 = __builtin_amdgcn_mfma_f32_32x32x16_bf16(a1, b1, acc11, 0, 0, 0);
    }

    // ---- epilogue: C layout col = lane&31, row = (reg&3)+8*(reg>>2)+4*lhi
    #pragma unroll
    for (int rt = 0; rt < 2; ++rt) {
      #pragma unroll
      for (int reg = 0; reg < 16; ++reg) {
        int row = (reg & 3) + 8 * (reg >> 2) + 4 * lhi;
        int grow = row0 + rt * 32 + row;
        if (grow < M) {
          float wv = hw ? hw[grow] : 1.f;
          #pragma unroll
          for (int ct = 0; ct < 2; ++ct) {
            int col = colbase + ct * 32 + l31;
            float v = ((rt == 0) ? (ct == 0 ? acc00[reg] : acc01[reg])
                                 : (ct == 0 ? acc10[reg] : acc11[reg])) + biasv[ct];
            v *= wv;
            if (O_F32) {
              ((float*)outv)[(size_t)grow * D + col] = v;
            } else {
              ((unsigned short*)outv)[(size_t)grow * D + col] = f2bf(v);
            }
          }
        }
      }
    }
    __syncthreads();  // all waves done with As before next stage
  }
}

// ---------------------------------------------------------------------------
// Gather nodes -> hyperedge mean (bf16 in/out). One wave per hyperedge.
// Unrolled x4 for memory-level parallelism.
// ---------------------------------------------------------------------------
__global__ __launch_bounds__(256) void gather_he_kernel(
    const unsigned short* __restrict__ xt, const int* __restrict__ he_start,
    const int* __restrict__ he_deg, const int* __restrict__ he_list,
    unsigned short* __restrict__ he_out) {
  int e = blockIdx.x * 4 + (threadIdx.x >> 6);
  if (e >= N_HE) return;
  int lane = threadIdx.x & 63;
  int s = he_start[e];
  int deg = he_deg[e];

  float a0 = 0.f, a1 = 0.f, a2 = 0.f, a3 = 0.f;
  int i = 0;
  for (; i + 4 <= deg; i += 4) {
    int n0 = he_list[s + i + 0];
    int n1 = he_list[s + i + 1];
    int n2 = he_list[s + i + 2];
    int n3 = he_list[s + i + 3];
    ushort4v v0 = ((const ushort4v*)(xt + (size_t)n0 * D))[lane];
    ushort4v v1 = ((const ushort4v*)(xt + (size_t)n1 * D))[lane];
    ushort4v v2 = ((const ushort4v*)(xt + (size_t)n2 * D))[lane];
    ushort4v v3 = ((const ushort4v*)(xt + (size_t)n3 * D))[lane];
    a0 += bf2f(v0[0]) + bf2f(v1[0]) + bf2f(v2[0]) + bf2f(v3[0]);
    a1 += bf2f(v0[1]) + bf2f(v1[1]) + bf2f(v2[1]) + bf2f(v3[1]);
    a2 += bf2f(v0[2]) + bf2f(v1[2]) + bf2f(v2[2]) + bf2f(v3[2]);
    a3 += bf2f(v0[3]) + bf2f(v1[3]) + bf2f(v2[3]) + bf2f(v3[3]);
  }
  for (; i < deg; ++i) {
    int n = he_list[s + i];
    ushort4v v = ((const ushort4v*)(xt + (size_t)n * D))[lane];
    a0 += bf2f(v[0]); a1 += bf2f(v[1]); a2 += bf2f(v[2]); a3 += bf2f(v[3]);
  }
  float inv = 1.0f / ((float)deg + MEAN_EPS);
  ushort4v o;
  o[0] = f2bf(a0 * inv); o[1] = f2bf(a1 * inv);
  o[2] = f2bf(a2 * inv); o[3] = f2bf(a3 * inv);
  ((ushort4v*)(he_out + (size_t)e * D))[lane] = o;
}

// ---------------------------------------------------------------------------
// Fused: gather hyperedges -> node mean, + xt residual, LayerNorm, LeakyReLU,
// optional outer residual. One wave per node. Unrolled x4.
// ---------------------------------------------------------------------------
__global__ __launch_bounds__(256) void gather_node_finalize(
    const unsigned short* __restrict__ he_feat, const int* __restrict__ n_start,
    const int* __restrict__ n_deg, const int* __restrict__ n_list,
    const unsigned short* __restrict__ xt, const float* __restrict__ g,
    const float* __restrict__ b, const float* __restrict__ res,
    float* __restrict__ out, int add_res) {
  int node = blockIdx.x * 4 + (threadIdx.x >> 6);
  if (node >= N_NODES) return;
  int lane = threadIdx.x & 63;
  int s = n_start[node];
  int deg = n_deg[node];

  float a0 = 0.f, a1 = 0.f, a2 = 0.f, a3 = 0.f;
  int i = 0;
  for (; i + 4 <= deg; i += 4) {
    int e0 = n_list[s + i + 0];
    int e1 = n_list[s + i + 1];
    int e2 = n_list[s + i + 2];
    int e3 = n_list[s + i + 3];
    ushort4v v0 = ((const ushort4v*)(he_feat + (size_t)e0 * D))[lane];
    ushort4v v1 = ((const ushort4v*)(he_feat + (size_t)e1 * D))[lane];
    ushort4v v2 = ((const ushort4v*)(he_feat + (size_t)e2 * D))[lane];
    ushort4v v3 = ((const ushort4v*)(he_feat + (size_t)e3 * D))[lane];
    a0 += bf2f(v0[0]) + bf2f(v1[0]) + bf2f(v2[0]) + bf2f(v3[0]);
    a1 += bf2f(v0[1]) + bf2f(v1[1]) + bf2f(v2[1]) + bf2f(v3[1]);
    a2 += bf2f(v0[2]) + bf2f(v1[2]) + bf2f(v2[2]) + bf2f(v3[2]);
    a3 += bf2f(v0[3]) + bf2f(v1[3]) + bf2f(v2[3]) + bf2f(v3[3]);
  }
  for (; i < deg; ++i) {
    int e = n_list[s + i];
    ushort4v v = ((const ushort4v*)(he_feat + (size_t)e * D))[lane];
    a0 += bf2f(v[0]); a1 += bf2f(v[1]); a2 += bf2f(v[2]); a3 += bf2f(v[3]);
  }
  float inv = deg > 0 ? 1.0f / (float)deg : 0.0f;

  ushort4v xv = ((const ushort4v*)(xt + (size_t)node * D))[lane];
  float h0 = a0 * inv + bf2f(xv[0]);
  float h1 = a1 * inv + bf2f(xv[1]);
  float h2 = a2 * inv + bf2f(xv[2]);
  float h3 = a3 * inv + bf2f(xv[3]);

  float sum = h0 + h1 + h2 + h3;
  float ss  = h0 * h0 + h1 * h1 + h2 * h2 + h3 * h3;
  #pragma unroll
  for (int o = 32; o > 0; o >>= 1) {
    sum += __shfl_xor(sum, o, 64);
    ss  += __shfl_xor(ss, o, 64);
  }
  float mu  = sum * (1.0f / D);
  float var = ss * (1.0f / D) - mu * mu;
  float rstd = rsqrtf(var + LN_EPS);

  float4 gv = ((const float4*)g)[lane];
  float4 bv = ((const float4*)b)[lane];

  float o0 = (h0 - mu) * rstd * gv.x + bv.x;
  float o1 = (h1 - mu) * rstd * gv.y + bv.y;
  float o2 = (h2 - mu) * rstd * gv.z + bv.z;
  float o3 = (h3 - mu) * rstd * gv.w + bv.w;
  o0 = o0 >= 0.f ? o0 : o0 * SLOPE;
  o1 = o1 >= 0.f ? o1 : o1 * SLOPE;
  o2 = o2 >= 0.f ? o2 : o2 * SLOPE;
  o3 = o3 >= 0.f ? o3 : o3 * SLOPE;

  if (add_res) {
    float4 rv = ((const float4*)(res + (size_t)node * D))[lane];
    o0 += rv.x; o1 += rv.y; o2 += rv.z; o3 += rv.w;
  }

  ((float4*)(out + (size_t)node * D))[lane] = make_float4(o0, o1, o2, o3);
}

// ---------------------------------------------------------------------------
extern "C" void kernel_launch(void* const* d_in, const int* in_sizes, int n_in,
                              void* d_out, int out_size, void* d_ws, size_t ws_size,
                              hipStream_t stream) {
  const float* x       = (const float*)d_in[0];
  const float* node_W  = (const float*)d_in[1];  // [2,256,256]
  const float* node_b  = (const float*)d_in[2];  // [2,256]
  const float* he_W    = (const float*)d_in[3];
  const float* he_b    = (const float*)d_in[4];
  const float* ln_g    = (const float*)d_in[5];
  const float* ln_b    = (const float*)d_in[6];
  const float* hw      = (const float*)d_in[7];  // [25000]
  const int*   node_idx = (const int*)d_in[8];
  const int*   he_idx   = (const int*)d_in[9];
  float* out = (float*)d_out;

  // Workspace layout (bf16 intermediates)
  unsigned short* xt     = (unsigned short*)d_ws;           // 100000*256 bf16
  unsigned short* he_buf = xt + (size_t)N_NODES * D;        // 25000*256 bf16
  unsigned short* Wt_node = he_buf + (size_t)N_HE * D;      // 2*65536 bf16
  unsigned short* Wt_he   = Wt_node + 2 * 65536;            // 2*65536 bf16
  int* he_deg   = (int*)(Wt_he + 2 * 65536);                // 25000
  int* n_deg    = he_deg + N_HE;                            // 100000
  int* totals   = n_deg + N_NODES;                          // 2
  int* he_start = totals + 2;                               // 25000
  int* he_cur   = he_start + N_HE;                          // 25000
  int* n_start  = he_cur + N_HE;                            // 100000
  int* n_cur    = n_start + N_NODES;                        // 100000
  int* he_list  = n_cur + N_NODES;                          // 400000
  int* n_list   = he_list + N_CONN;                         // 400000

  // --- Weight convert+transpose (both layers) ---
  convert_w<<<32, 256, 0, stream>>>(node_W, Wt_node);
  convert_w<<<32, 256, 0, stream>>>(he_W, Wt_he);

  // --- Build adjacency (every call; indices are constant inputs) ---
  hipMemsetAsync(he_deg, 0, (size_t)(N_HE + N_NODES + 2) * sizeof(int), stream);
  hist_kernel<<<(N_CONN + 255) / 256, 256, 0, stream>>>(node_idx, he_idx, he_deg, n_deg);
  alloc_kernel<<<(N_NODES + 255) / 256, 256, 0, stream>>>(
      he_deg, n_deg, totals, he_start, he_cur, n_start, n_cur);
  fill_kernel<<<(N_CONN + 255) / 256, 256, 0, stream>>>(
      node_idx, he_idx, he_cur, n_cur, he_list, n_list);

  const int ntiles_node = (N_NODES + 63) / 64;  // 1563
  const int ntiles_he   = (N_HE + 63) / 64;     // 391
  const int grid_node = 512;                    // 2 blocks/CU resident
  const int grid_he   = ntiles_he;

  for (int l = 0; l < 2; ++l) {
    const float* xin = (l == 0) ? x : out;
    const float* bn = node_b + (size_t)l * D;
    const float* be = he_b + (size_t)l * D;
    const float* g  = ln_g + (size_t)l * D;
    const float* bb = ln_b + (size_t)l * D;

    gemm32<1, 0><<<grid_node, 256, 0, stream>>>(
        xin, Wt_node + (size_t)l * 65536, bn, nullptr, xt, N_NODES, ntiles_node);
    gather_he_kernel<<<(N_HE + 3) / 4, 256, 0, stream>>>(
        xt, he_start, he_deg, he_list, he_buf);
    gemm32<0, 0><<<grid_he, 256, 0, stream>>>(
        he_buf, Wt_he + (size_t)l * 65536, be, hw, he_buf, N_HE, ntiles_he);
    gather_node_finalize<<<(N_NODES + 3) / 4, 256, 0, stream>>>(
        he_buf, n_start, n_deg, n_list, xt, g, bb, xin, out, l);
  }
}

// Round 7
// 464.319 us; speedup vs baseline: 13.8193x; 1.0205x over previous
//
#include <hip/hip_runtime.h>

#define D 256
#define N_NODES 100000
#define N_HE 25000
#define N_CONN 400000

constexpr float MEAN_EPS = 1e-8f;
constexpr float LN_EPS   = 1e-5f;
constexpr float SLOPE    = 0.2f;

typedef __attribute__((ext_vector_type(8))) short short8;
typedef __attribute__((ext_vector_type(4))) float f32x4;
typedef __attribute__((ext_vector_type(16))) float f32x16;
typedef __attribute__((ext_vector_type(4))) unsigned short ushort4v;

static __device__ __forceinline__ unsigned short f2bf(float f) {
  unsigned int u = __builtin_bit_cast(unsigned int, f);
  u = (u + 0x7FFFu + ((u >> 16) & 1u)) >> 16;
  return (unsigned short)u;
}
static __device__ __forceinline__ float bf2f(unsigned short u) {
  return __builtin_bit_cast(float, (unsigned int)u << 16);
}

// ---------------------------------------------------------------------------
// Adjacency build (indices are constant inputs; rebuilt every call)
// ---------------------------------------------------------------------------
__global__ __launch_bounds__(256) void hist_kernel(
    const int* __restrict__ node_idx, const int* __restrict__ he_idx,
    int* __restrict__ he_deg, int* __restrict__ n_deg) {
  int c = blockIdx.x * 256 + threadIdx.x;
  if (c < N_CONN) {
    atomicAdd(&he_deg[he_idx[c]], 1);
    atomicAdd(&n_deg[node_idx[c]], 1);
  }
}

__global__ __launch_bounds__(256) void alloc_kernel(
    const int* __restrict__ he_deg, const int* __restrict__ n_deg,
    int* __restrict__ totals,
    int* __restrict__ he_start, int* __restrict__ he_cur,
    int* __restrict__ n_start, int* __restrict__ n_cur) {
  int i = blockIdx.x * 256 + threadIdx.x;
  if (i < N_HE) {
    int s = atomicAdd(&totals[0], he_deg[i]);
    he_start[i] = s;
    he_cur[i] = s;
  }
  if (i < N_NODES) {
    int s = atomicAdd(&totals[1], n_deg[i]);
    n_start[i] = s;
    n_cur[i] = s;
  }
}

__global__ __launch_bounds__(256) void fill_kernel(
    const int* __restrict__ node_idx, const int* __restrict__ he_idx,
    int* __restrict__ he_cur, int* __restrict__ n_cur,
    int* __restrict__ he_list, int* __restrict__ n_list) {
  int c = blockIdx.x * 256 + threadIdx.x;
  if (c < N_CONN) {
    int n = node_idx[c];
    int e = he_idx[c];
    int p = atomicAdd(&he_cur[e], 1);
    he_list[p] = n;
    int q = atomicAdd(&n_cur[n], 1);
    n_list[q] = e;
  }
}

// ---------------------------------------------------------------------------
// Weight convert+transpose: Wt[n][k] = bf16(W[k][n]). One 64x64 tile/block.
// ---------------------------------------------------------------------------
__global__ __launch_bounds__(256) void convert_w(
    const float* __restrict__ W, unsigned short* __restrict__ Wt) {
  int m = blockIdx.x >> 4;
  int tile = blockIdx.x & 15;
  int k0 = (tile >> 2) * 64, n0 = (tile & 3) * 64;
  const float* Win = W + (size_t)m * 65536;
  unsigned short* Wout = Wt + (size_t)m * 65536;
  __shared__ unsigned short T[64][65];
  int t = threadIdx.x;
  int r = t >> 6, c = t & 63;
  #pragma unroll 4
  for (int i = 0; i < 16; ++i) {
    int kr = i * 4 + r;
    T[kr][c] = f2bf(Win[(size_t)(k0 + kr) * 256 + n0 + c]);
  }
  __syncthreads();
  #pragma unroll 4
  for (int i = 0; i < 16; ++i) {
    int nr = i * 4 + r;
    Wout[(size_t)(n0 + nr) * 256 + k0 + c] = T[c][nr];
  }
}

// ---------------------------------------------------------------------------
// 32x32x16 MFMA GEMM, weight-stationary-in-regs, low footprint for occupancy.
// out[r][c] = (A[r][:].W[:][c] + bias[c]) [* hw[r] if hw]
// Block = 64 rows x 256 cols, 512 threads / 8 waves; wave owns 32 cols.
// B: 16 fragments (64 VGPR), loaded once, asm-pinned. A staged bf16 in LDS
// with involutive XOR swizzle. One tile per block (grid = ntiles).
// Reg budget/wave: B 64 + acc 32 + a 16 + misc ~16 ≈ 128 -> 2 blocks/CU.
// In-place safe (tile fully staged before stores; rows block-private).
// ---------------------------------------------------------------------------
template <int A_F32, int O_F32>
__global__ __launch_bounds__(512, 4) void gemm32(
    const void* __restrict__ Ain, const unsigned short* __restrict__ Wt,
    const float* __restrict__ bias, const float* __restrict__ hw,
    void* __restrict__ outv, int M) {
  __shared__ unsigned short As[64 * 256];  // 32 KB [row][k] bf16, swizzled
  const int t = threadIdx.x;
  const int wave = t >> 6, lane = t & 63;
  const int l31 = lane & 31, lhi = lane >> 5;
  const int colbase = wave * 32;
  const int row0 = blockIdx.x * 64;

  // ---- preload + pin B fragments: lane l31 = col, lhi = k-half ----
  f32x4 B[16];
  {
    const unsigned short* bp = Wt + (size_t)(colbase + l31) * 256 + lhi * 8;
    #pragma unroll
    for (int kc = 0; kc < 16; ++kc)
      B[kc] = *(const f32x4*)(bp + kc * 16);
  }
  #pragma unroll
  for (int kc = 0; kc < 16; ++kc)
    asm volatile("" : "+v"(B[kc]));

  float biasv = bias[colbase + l31];

  // ---- stage A tile (-> bf16, XOR swizzle), 512 threads ----
  if (A_F32) {
    const float* A = (const float*)Ain;
    #pragma unroll
    for (int i = 0; i < 8; ++i) {
      int row = i * 8 + (t >> 6);
      int col4 = t & 63;
      int r = row0 + row;
      float4 v = (r < M) ? ((const float4*)(A + (size_t)r * D))[col4]
                         : make_float4(0.f, 0.f, 0.f, 0.f);
      ushort4v o;
      o[0] = f2bf(v.x); o[1] = f2bf(v.y); o[2] = f2bf(v.z); o[3] = f2bf(v.w);
      unsigned int byte = (unsigned)(row * 512 + col4 * 8) ^ (unsigned)((row & 7) << 4);
      *(ushort4v*)((char*)As + byte) = o;
    }
  } else {
    const unsigned short* A = (const unsigned short*)Ain;
    #pragma unroll
    for (int i = 0; i < 4; ++i) {
      int row = i * 16 + (t >> 5);
      int e = t & 31;
      int r = row0 + row;
      short8 v = {};
      if (r < M) v = *(const short8*)(A + (size_t)r * D + e * 8);
      unsigned int byte = (unsigned)(row * 512 + e * 16) ^ (unsigned)((row & 7) << 4);
      *(short8*)((char*)As + byte) = v;
    }
  }
  __syncthreads();

  // ---- 16 k-steps: 2 ds_read_b128 + 2 MFMA each ----
  f32x16 acc0 = (f32x16)0.f, acc1 = (f32x16)0.f;
  #pragma unroll
  for (int kc = 0; kc < 16; ++kc) {
    int r0 = l31;
    unsigned int ad0 = (unsigned)(r0 * 512 + kc * 32 + lhi * 16) ^ (unsigned)((r0 & 7) << 4);
    short8 a0 = *(const short8*)((const char*)As + ad0);
    int r1 = 32 + l31;
    unsigned int ad1 = (unsigned)(r1 * 512 + kc * 32 + lhi * 16) ^ (unsigned)((r1 & 7) << 4);
    short8 a1 = *(const short8*)((const char*)As + ad1);
    short8 b = __builtin_bit_cast(short8, B[kc]);
    acc0 = __builtin_amdgcn_mfma_f32_32x32x16_bf16(a0, b, acc0, 0, 0, 0);
    acc1 = __builtin_amdgcn_mfma_f32_32x32x16_bf16(a1, b, acc1, 0, 0, 0);
  }

  // ---- epilogue: C layout col = lane&31, row = (reg&3)+8*(reg>>2)+4*lhi ----
  const int col = colbase + l31;
  #pragma unroll
  for (int rt = 0; rt < 2; ++rt) {
    #pragma unroll
    for (int reg = 0; reg < 16; ++reg) {
      int row = (reg & 3) + 8 * (reg >> 2) + 4 * lhi;
      int grow = row0 + rt * 32 + row;
      if (grow < M) {
        float wv = hw ? hw[grow] : 1.f;
        float v = ((rt == 0) ? acc0[reg] : acc1[reg]) + biasv;
        v *= wv;
        if (O_F32) {
          ((float*)outv)[(size_t)grow * D + col] = v;
        } else {
          ((unsigned short*)outv)[(size_t)grow * D + col] = f2bf(v);
        }
      }
    }
  }
}

// ---------------------------------------------------------------------------
// Gather nodes -> hyperedge mean (bf16 in/out). One wave per hyperedge.
// Unrolled x4 for memory-level parallelism.
// ---------------------------------------------------------------------------
__global__ __launch_bounds__(256) void gather_he_kernel(
    const unsigned short* __restrict__ xt, const int* __restrict__ he_start,
    const int* __restrict__ he_deg, const int* __restrict__ he_list,
    unsigned short* __restrict__ he_out) {
  int e = blockIdx.x * 4 + (threadIdx.x >> 6);
  if (e >= N_HE) return;
  int lane = threadIdx.x & 63;
  int s = he_start[e];
  int deg = he_deg[e];

  float a0 = 0.f, a1 = 0.f, a2 = 0.f, a3 = 0.f;
  int i = 0;
  for (; i + 4 <= deg; i += 4) {
    int n0 = he_list[s + i + 0];
    int n1 = he_list[s + i + 1];
    int n2 = he_list[s + i + 2];
    int n3 = he_list[s + i + 3];
    ushort4v v0 = ((const ushort4v*)(xt + (size_t)n0 * D))[lane];
    ushort4v v1 = ((const ushort4v*)(xt + (size_t)n1 * D))[lane];
    ushort4v v2 = ((const ushort4v*)(xt + (size_t)n2 * D))[lane];
    ushort4v v3 = ((const ushort4v*)(xt + (size_t)n3 * D))[lane];
    a0 += bf2f(v0[0]) + bf2f(v1[0]) + bf2f(v2[0]) + bf2f(v3[0]);
    a1 += bf2f(v0[1]) + bf2f(v1[1]) + bf2f(v2[1]) + bf2f(v3[1]);
    a2 += bf2f(v0[2]) + bf2f(v1[2]) + bf2f(v2[2]) + bf2f(v3[2]);
    a3 += bf2f(v0[3]) + bf2f(v1[3]) + bf2f(v2[3]) + bf2f(v3[3]);
  }
  for (; i < deg; ++i) {
    int n = he_list[s + i];
    ushort4v v = ((const ushort4v*)(xt + (size_t)n * D))[lane];
    a0 += bf2f(v[0]); a1 += bf2f(v[1]); a2 += bf2f(v[2]); a3 += bf2f(v[3]);
  }
  float inv = 1.0f / ((float)deg + MEAN_EPS);
  ushort4v o;
  o[0] = f2bf(a0 * inv); o[1] = f2bf(a1 * inv);
  o[2] = f2bf(a2 * inv); o[3] = f2bf(a3 * inv);
  ((ushort4v*)(he_out + (size_t)e * D))[lane] = o;
}

// ---------------------------------------------------------------------------
// Fused: gather hyperedges -> node mean, + xt residual, LayerNorm, LeakyReLU,
// optional outer residual. One wave per node. Unrolled x4.
// ---------------------------------------------------------------------------
__global__ __launch_bounds__(256) void gather_node_finalize(
    const unsigned short* __restrict__ he_feat, const int* __restrict__ n_start,
    const int* __restrict__ n_deg, const int* __restrict__ n_list,
    const unsigned short* __restrict__ xt, const float* __restrict__ g,
    const float* __restrict__ b, const float* __restrict__ res,
    float* __restrict__ out, int add_res) {
  int node = blockIdx.x * 4 + (threadIdx.x >> 6);
  if (node >= N_NODES) return;
  int lane = threadIdx.x & 63;
  int s = n_start[node];
  int deg = n_deg[node];

  float a0 = 0.f, a1 = 0.f, a2 = 0.f, a3 = 0.f;
  int i = 0;
  for (; i + 4 <= deg; i += 4) {
    int e0 = n_list[s + i + 0];
    int e1 = n_list[s + i + 1];
    int e2 = n_list[s + i + 2];
    int e3 = n_list[s + i + 3];
    ushort4v v0 = ((const ushort4v*)(he_feat + (size_t)e0 * D))[lane];
    ushort4v v1 = ((const ushort4v*)(he_feat + (size_t)e1 * D))[lane];
    ushort4v v2 = ((const ushort4v*)(he_feat + (size_t)e2 * D))[lane];
    ushort4v v3 = ((const ushort4v*)(he_feat + (size_t)e3 * D))[lane];
    a0 += bf2f(v0[0]) + bf2f(v1[0]) + bf2f(v2[0]) + bf2f(v3[0]);
    a1 += bf2f(v0[1]) + bf2f(v1[1]) + bf2f(v2[1]) + bf2f(v3[1]);
    a2 += bf2f(v0[2]) + bf2f(v1[2]) + bf2f(v2[2]) + bf2f(v3[2]);
    a3 += bf2f(v0[3]) + bf2f(v1[3]) + bf2f(v2[3]) + bf2f(v3[3]);
  }
  for (; i < deg; ++i) {
    int e = n_list[s + i];
    ushort4v v = ((const ushort4v*)(he_feat + (size_t)e * D))[lane];
    a0 += bf2f(v[0]); a1 += bf2f(v[1]); a2 += bf2f(v[2]); a3 += bf2f(v[3]);
  }
  float inv = deg > 0 ? 1.0f / (float)deg : 0.0f;

  ushort4v xv = ((const ushort4v*)(xt + (size_t)node * D))[lane];
  float h0 = a0 * inv + bf2f(xv[0]);
  float h1 = a1 * inv + bf2f(xv[1]);
  float h2 = a2 * inv + bf2f(xv[2]);
  float h3 = a3 * inv + bf2f(xv[3]);

  float sum = h0 + h1 + h2 + h3;
  float ss  = h0 * h0 + h1 * h1 + h2 * h2 + h3 * h3;
  #pragma unroll
  for (int o = 32; o > 0; o >>= 1) {
    sum += __shfl_xor(sum, o, 64);
    ss  += __shfl_xor(ss, o, 64);
  }
  float mu  = sum * (1.0f / D);
  float var = ss * (1.0f / D) - mu * mu;
  float rstd = rsqrtf(var + LN_EPS);

  float4 gv = ((const float4*)g)[lane];
  float4 bv = ((const float4*)b)[lane];

  float o0 = (h0 - mu) * rstd * gv.x + bv.x;
  float o1 = (h1 - mu) * rstd * gv.y + bv.y;
  float o2 = (h2 - mu) * rstd * gv.z + bv.z;
  float o3 = (h3 - mu) * rstd * gv.w + bv.w;
  o0 = o0 >= 0.f ? o0 : o0 * SLOPE;
  o1 = o1 >= 0.f ? o1 : o1 * SLOPE;
  o2 = o2 >= 0.f ? o2 : o2 * SLOPE;
  o3 = o3 >= 0.f ? o3 : o3 * SLOPE;

  if (add_res) {
    float4 rv = ((const float4*)(res + (size_t)node * D))[lane];
    o0 += rv.x; o1 += rv.y; o2 += rv.z; o3 += rv.w;
  }

  ((float4*)(out + (size_t)node * D))[lane] = make_float4(o0, o1, o2, o3);
}

// ---------------------------------------------------------------------------
extern "C" void kernel_launch(void* const* d_in, const int* in_sizes, int n_in,
                              void* d_out, int out_size, void* d_ws, size_t ws_size,
                              hipStream_t stream) {
  const float* x       = (const float*)d_in[0];
  const float* node_W  = (const float*)d_in[1];  // [2,256,256]
  const float* node_b  = (const float*)d_in[2];  // [2,256]
  const float* he_W    = (const float*)d_in[3];
  const float* he_b    = (const float*)d_in[4];
  const float* ln_g    = (const float*)d_in[5];
  const float* ln_b    = (const float*)d_in[6];
  const float* hw      = (const float*)d_in[7];  // [25000]
  const int*   node_idx = (const int*)d_in[8];
  const int*   he_idx   = (const int*)d_in[9];
  float* out = (float*)d_out;

  // Workspace layout (bf16 intermediates)
  unsigned short* xt     = (unsigned short*)d_ws;           // 100000*256 bf16
  unsigned short* he_buf = xt + (size_t)N_NODES * D;        // 25000*256 bf16
  unsigned short* Wt_node = he_buf + (size_t)N_HE * D;      // 2*65536 bf16
  unsigned short* Wt_he   = Wt_node + 2 * 65536;            // 2*65536 bf16
  int* he_deg   = (int*)(Wt_he + 2 * 65536);                // 25000
  int* n_deg    = he_deg + N_HE;                            // 100000
  int* totals   = n_deg + N_NODES;                          // 2
  int* he_start = totals + 2;                               // 25000
  int* he_cur   = he_start + N_HE;                          // 25000
  int* n_start  = he_cur + N_HE;                            // 100000
  int* n_cur    = n_start + N_NODES;                        // 100000
  int* he_list  = n_cur + N_NODES;                          // 400000
  int* n_list   = he_list + N_CONN;                         // 400000

  // --- Weight convert+transpose (both layers) ---
  convert_w<<<32, 256, 0, stream>>>(node_W, Wt_node);
  convert_w<<<32, 256, 0, stream>>>(he_W, Wt_he);

  // --- Build adjacency (every call; indices are constant inputs) ---
  hipMemsetAsync(he_deg, 0, (size_t)(N_HE + N_NODES + 2) * sizeof(int), stream);
  hist_kernel<<<(N_CONN + 255) / 256, 256, 0, stream>>>(node_idx, he_idx, he_deg, n_deg);
  alloc_kernel<<<(N_NODES + 255) / 256, 256, 0, stream>>>(
      he_deg, n_deg, totals, he_start, he_cur, n_start, n_cur);
  fill_kernel<<<(N_CONN + 255) / 256, 256, 0, stream>>>(
      node_idx, he_idx, he_cur, n_cur, he_list, n_list);

  const int ntiles_node = (N_NODES + 63) / 64;  // 1563
  const int ntiles_he   = (N_HE + 63) / 64;     // 391

  for (int l = 0; l < 2; ++l) {
    const float* xin = (l == 0) ? x : out;
    const float* bn = node_b + (size_t)l * D;
    const float* be = he_b + (size_t)l * D;
    const float* g  = ln_g + (size_t)l * D;
    const float* bb = ln_b + (size_t)l * D;

    gemm32<1, 0><<<ntiles_node, 512, 0, stream>>>(
        xin, Wt_node + (size_t)l * 65536, bn, nullptr, xt, N_NODES);
    gather_he_kernel<<<(N_HE + 3) / 4, 256, 0, stream>>>(
        xt, he_start, he_deg, he_list, he_buf);
    gemm32<0, 0><<<ntiles_he, 512, 0, stream>>>(
        he_buf, Wt_he + (size_t)l * 65536, be, hw, he_buf, N_HE);
    gather_node_finalize<<<(N_NODES + 3) / 4, 256, 0, stream>>>(
        he_buf, n_start, n_deg, n_list, xt, g, bb, xin, out, l);
  }
}